// Round 4
// baseline (568.051 us; speedup 1.0000x reference)
//
#include <hip/hip_runtime.h>

#define Bn 4
#define Sn 2048
#define Dn 1024
#define Hn 16
#define DHn 64

typedef float f32x4 __attribute__((ext_vector_type(4)));
typedef short bf16x8 __attribute__((ext_vector_type(8)));
typedef unsigned short u16;
typedef unsigned int u32;
typedef unsigned short u16x8 __attribute__((ext_vector_type(8)));
typedef unsigned short u16x4 __attribute__((ext_vector_type(4)));
typedef u32 u32x4 __attribute__((ext_vector_type(4)));

union B8 { u32x4 u; bf16x8 s; u16x8 h; };

__device__ __forceinline__ u16 f2bf(float f){
  union { float f; u32 u; } v; v.f = f;
  return (u16)((v.u + 0x7fffu + ((v.u >> 16) & 1u)) >> 16);
}

// truncating pack: two fp32 -> {bf16(lo) | bf16(hi)<<16}. P>0 -> -0.2% uniform bias, negligible.
__device__ __forceinline__ u32 pack_bf2(float lo, float hi){
  union { float f; u32 u; } a, b;
  a.f = lo; b.f = hi;
  return __builtin_amdgcn_perm(b.u, a.u, 0x07060302u);
}

#if __has_builtin(__builtin_amdgcn_exp2f)
#define EXP2(x) __builtin_amdgcn_exp2f(x)
#define QSCALE 0.18033688011112042f   /* 0.125 * log2(e) */
#else
#define EXP2(x) __expf(x)
#define QSCALE 0.125f
#endif

#if __has_builtin(__builtin_amdgcn_global_load_lds)
#define G2L16(l, g) __builtin_amdgcn_global_load_lds((const __attribute__((address_space(1))) u32*)(g), \
                                                     (__attribute__((address_space(3))) u32*)(l), 16, 0, 0)
#else
#define G2L16(l, g) (*(bf16x8*)(l) = *(const bf16x8*)(g))
#endif

#define MFMA_B16(d, va, vb) (d) = __builtin_amdgcn_mfma_f32_16x16x32_bf16((va), (vb), (d), 0, 0, 0)
#define BARRAW() __builtin_amdgcn_s_barrier()
#define WAIT_LGKM0() asm volatile("s_waitcnt lgkmcnt(0)" ::: "memory")
#define VM4() asm volatile("s_waitcnt vmcnt(4)" ::: "memory")
#define VM2() asm volatile("s_waitcnt vmcnt(2)" ::: "memory")
#define VM0() asm volatile("s_waitcnt vmcnt(0)" ::: "memory")
#define SCHEDB() __builtin_amdgcn_sched_barrier(0)

// ---------------- merged prep: cast x (blocks 0..4095) + 4 weights (4096..5119) ----------------
__global__ void prep_kernel(const float* __restrict__ x,
                            const float* __restrict__ Wq, const float* __restrict__ Wk,
                            const float* __restrict__ Wv, const float* __restrict__ Wo,
                            u16* __restrict__ xb, u16* __restrict__ wt_all){
  __shared__ u16 tile[64*66];
  const int t = threadIdx.x;
  if (blockIdx.x < 4096){
    size_t i = ((size_t)blockIdx.x * 256 + t) * 8;
    float4 f0 = *(const float4*)(x + i);
    float4 f1 = *(const float4*)(x + i + 4);
    u16x8 o;
    o[0]=f2bf(f0.x); o[1]=f2bf(f0.y); o[2]=f2bf(f0.z); o[3]=f2bf(f0.w);
    o[4]=f2bf(f1.x); o[5]=f2bf(f1.y); o[6]=f2bf(f1.z); o[7]=f2bf(f1.w);
    *(u16x8*)(xb + i) = o;
    return;
  }
  const int wi = blockIdx.x - 4096;
  const int z = wi >> 8, r8 = wi & 255;
  const int k0 = (r8 >> 4) * 64, n0 = (r8 & 15) * 64;
  const float* w = (z == 0) ? Wq : (z == 1) ? Wk : (z == 2) ? Wv : Wo;
  const float scale = (z == 0) ? QSCALE : 1.0f;
  u16* wt = wt_all + (size_t)z * Dn * Dn;
  #pragma unroll
  for (int i = 0; i < 4; i++){
    int idx = i*256 + t;
    int r = idx >> 4, c4 = (idx & 15) * 4;
    float4 f = *(const float4*)(w + (size_t)(k0 + r)*Dn + n0 + c4);
    tile[r*66 + c4 + 0] = f2bf(f.x * scale);
    tile[r*66 + c4 + 1] = f2bf(f.y * scale);
    tile[r*66 + c4 + 2] = f2bf(f.z * scale);
    tile[r*66 + c4 + 3] = f2bf(f.w * scale);
  }
  __syncthreads();
  #pragma unroll
  for (int i = 0; i < 4; i++){
    int idx = i*256 + t;
    int nr = idx >> 4, kc4 = (idx & 15) * 4;
    u16x4 o;
    o[0] = tile[(kc4+0)*66 + nr];
    o[1] = tile[(kc4+1)*66 + nr];
    o[2] = tile[(kc4+2)*66 + nr];
    o[3] = tile[(kc4+3)*66 + nr];
    *(u16x4*)(wt + (size_t)(n0 + nr)*Dn + k0 + kc4) = o;
  }
}

// ---------------- QKV GEMM: 128^2 tile, BK=64, A-tri/B-dbuf, 1 barrier/K-tile ----------------
__launch_bounds__(256)
__global__ void gemm_qkv_kernel(const u16* __restrict__ xb, const u16* __restrict__ wt_all,
                                u16* __restrict__ qb, u16* __restrict__ kb, u16* __restrict__ vtb){
  __shared__ u16 sm[40960];   // 80 KB
  const int t = threadIdx.x;
  const int lane = t & 63, wave = t >> 6;
  const int ln = lane & 15, quad = lane >> 4;
  const int wm = wave >> 1, wn = wave & 1;

  // T1: XCD-chunked bijective swizzle (1536 = 8*192), m-outer n-inner within chunk
  const int lin = blockIdx.x;
  const int wg = (lin & 7) * 192 + (lin >> 3);
  const int zsel = wg >> 9;
  const int rem = wg & 511;
  const int m0 = (rem >> 3) * 128;
  const int n0 = (rem & 7) * 128;
  const u16* wt = wt_all + (size_t)zsel * Dn * Dn;

  const u16* ap[4]; const u16* bp[4]; int ldo[4];
  #pragma unroll
  for (int p = 0; p < 4; p++){
    int idx = p*256 + t;
    int r = idx >> 3, g = (idx & 7) ^ (r & 7);
    ap[p] = xb + (size_t)(m0 + r)*Dn + g*8;
    bp[p] = wt + (size_t)(n0 + r)*Dn + g*8;
    ldo[p] = idx * 8;
  }
#define STGA(buf, tt) do { _Pragma("unroll") for (int p = 0; p < 4; p++) \
    G2L16(&sm[(buf) + ldo[p]], ap[p] + (size_t)(tt)*64); } while(0)
#define STGB(buf, tt) do { _Pragma("unroll") for (int p = 0; p < 4; p++) \
    G2L16(&sm[(buf) + ldo[p]], bp[p] + (size_t)(tt)*64); } while(0)

  const int agr0 = ((    quad) ^ (ln & 7)) * 8;
  const int agr1 = ((4 + quad) ^ (ln & 7)) * 8;
  int arow[4], brow[4];
  #pragma unroll
  for (int i = 0; i < 4; i++) arow[i] = (wm*64 + i*16 + ln) * 64;
  #pragma unroll
  for (int j = 0; j < 4; j++) brow[j] = (wn*64 + j*16 + ln) * 64;

  f32x4 acc[4][4] = {};

  STGA(0, 0); STGB(24576, 0); STGA(8192, 1);

  #pragma unroll
  for (int tt = 0; tt < 16; ++tt){
    const int a_cur = (tt % 3) * 8192;
    const int a_pf  = ((tt + 2) % 3) * 8192;
    const int b_cur = 24576 + (tt & 1) * 8192;
    const int b_pf  = 24576 + ((tt + 1) & 1) * 8192;

    if (tt < 15) { VM4(); } else { VM0(); }
    BARRAW(); SCHEDB();

    bf16x8 a01[2][2], bq[4][2];
    #pragma unroll
    for (int i = 0; i < 2; i++){
      a01[i][0] = *(const bf16x8*)&sm[a_cur + arow[i] + agr0];
      a01[i][1] = *(const bf16x8*)&sm[a_cur + arow[i] + agr1];
    }
    #pragma unroll
    for (int j = 0; j < 4; j++){
      bq[j][0] = *(const bf16x8*)&sm[b_cur + brow[j] + agr0];
      bq[j][1] = *(const bf16x8*)&sm[b_cur + brow[j] + agr1];
    }
    SCHEDB();
    if (tt < 15) STGB(b_pf, tt + 1);
    SCHEDB();
    WAIT_LGKM0(); SCHEDB();
    __builtin_amdgcn_s_setprio(1);
    #pragma unroll
    for (int i = 0; i < 2; i++)
      #pragma unroll
      for (int j = 0; j < 4; j++){
        MFMA_B16(acc[i][j], a01[i][0], bq[j][0]);
        MFMA_B16(acc[i][j], a01[i][1], bq[j][1]);
      }
    __builtin_amdgcn_s_setprio(0);

    bf16x8 a23[2][2];
    #pragma unroll
    for (int i = 0; i < 2; i++){
      a23[i][0] = *(const bf16x8*)&sm[a_cur + arow[2+i] + agr0];
      a23[i][1] = *(const bf16x8*)&sm[a_cur + arow[2+i] + agr1];
    }
    SCHEDB();
    if (tt < 14) STGA(a_pf, tt + 2);
    SCHEDB();
    WAIT_LGKM0(); SCHEDB();
    __builtin_amdgcn_s_setprio(1);
    #pragma unroll
    for (int i = 0; i < 2; i++)
      #pragma unroll
      for (int j = 0; j < 4; j++){
        MFMA_B16(acc[2+i][j], a23[i][0], bq[j][0]);
        MFMA_B16(acc[2+i][j], a23[i][1], bq[j][1]);
      }
    __builtin_amdgcn_s_setprio(0);
  }

  __syncthreads();
  u16* Cs = sm;
  if (zsel < 2){
    u16* outp = (zsel == 0) ? qb : kb;
    #pragma unroll
    for (int rb = 0; rb < 4; rb++)
      #pragma unroll
      for (int cb = 0; cb < 4; cb++)
        #pragma unroll
        for (int reg = 0; reg < 4; reg++)
          Cs[(wm*64 + rb*16 + quad*4 + reg)*136 + wn*64 + cb*16 + ln] = f2bf(acc[rb][cb][reg]);
    __syncthreads();
    #pragma unroll
    for (int i = 0; i < 8; i++){
      int idx = i*256 + t;
      int r = idx >> 4, c8 = (idx & 15) * 8;
      bf16x8 vdat = *(const bf16x8*)&Cs[r*136 + c8];
      int row = m0 + r, bb = row >> 11, s = row & 2047;
      int col = n0 + c8, hh = col >> 6, d = col & 63;
      *(bf16x8*)(outp + (((size_t)bb*Hn + hh)*Sn + s)*DHn + d) = vdat;
    }
  } else {
    #pragma unroll
    for (int rb = 0; rb < 4; rb++)
      #pragma unroll
      for (int cb = 0; cb < 4; cb++){
        u16x4 o;
        #pragma unroll
        for (int reg = 0; reg < 4; reg++) o[reg] = f2bf(acc[rb][cb][reg]);
        *(u16x4*)&Cs[(wn*64 + cb*16 + ln)*136 + wm*64 + rb*16 + quad*4] = o;
      }
    __syncthreads();
    #pragma unroll
    for (int i = 0; i < 8; i++){
      int idx = i*256 + t;
      int c = idx >> 4, r8 = (idx & 15) * 8;
      bf16x8 vdat = *(const bf16x8*)&Cs[c*136 + r8];
      int col = n0 + c, hh = col >> 6, d = col & 63;
      int row = m0 + r8, bb = row >> 11, s = row & 2047;
      *(bf16x8*)(vtb + (((size_t)bb*Hn + hh)*DHn + d)*Sn + s) = vdat;
    }
  }
#undef STGA
#undef STGB
}

// ---------------- attention: 8 waves x 32 q, deep-pipelined staging ----------------
// K: 4-deep LDS buffers via global_load_lds (pre-swizzled per-lane source,
//    prefetch distance 2, async DMA - no VGPR round trip).
// V: register prefetch distance 2 (2-reg rotation, compile-time via 4x unroll)
//    + LDS dbuf with column-shuffle write.
// Counted vmcnt(2) once per iter (drains exactly tile kt+1; K/V of kt+2 stay
// in flight across the barrier). Raw s_barrier + lgkm0. No vmcnt(0) in loop.
__launch_bounds__(512, 4)
__global__ void attn_kernel(const u16* q, const u16* __restrict__ k,
                            const u16* __restrict__ vt, u16* z){
  __shared__ u16 Ks[4][64*64];   // [key][d], swizzled granules, 4-deep
  __shared__ u16 Vs[2][64*64];   // [d][key'] column-shuffled + swizzled, 2-deep
  const int t = threadIdx.x;
  const int wave = t >> 6, lane = t & 63;
  const int ln = lane & 15, quad = lane >> 4;
  const int lin = blockIdx.x + 8*(blockIdx.y + 16*blockIdx.z);
  const int wgs = (lin & 7)*64 + (lin >> 3);
  const int qt = wgs & 7, h = (wgs >> 3) & 15, b = wgs >> 7;
  const size_t bh = (size_t)b * Hn + h;
  const int q0 = qt*256 + wave*32;
  const u16* qp = q + bh * Sn * DHn;
  const u16* kp = k + bh * Sn * DHn;
  const u16* vp = vt + bh * DHn * Sn;

  bf16x8 qf[2][2];
  #pragma unroll
  for (int n = 0; n < 2; n++)
    #pragma unroll
    for (int kq = 0; kq < 2; kq++)
      qf[n][kq] = *(const bf16x8*)(qp + (size_t)(q0 + n*16 + ln)*DHn + kq*32 + quad*8);

  f32x4 zacc[4][2] = {};
  float dacc[2] = {0.f, 0.f};

  // staging coords: thread t handles granule a of row r (512 thr = 64x8 granules)
  const int r = t >> 3, a = t & 7;
  // K: G2L16 with pre-swizzled global source, linear LDS dest (t*16 bytes)
  const u16* kgp = kp + (size_t)r*DHn + ((a ^ (r & 7)) * 8);
  const int kldo = t * 8;   // u16 offset
#define STGK(buf, tt) G2L16(&Ks[buf][kldo], kgp + (size_t)(tt)*4096)
  // V: register-staged, column-shuffled + swizzled write
  const int ksg = a >> 2, q1 = ((a&3)*2)&3, h1 = (a&3) >> 1;
  const int vc1 = ksg*32 + q1*8 + h1*4;
  const int vc2 = ksg*32 + (((q1+1)&3))*8 + h1*4;
  const int vpos1 = r*64 + ((vc1>>3) ^ (r&7))*8 + (vc1 & 7);
  const int vpos2 = r*64 + ((vc2>>3) ^ (r&7))*8 + (vc2 & 7);
  const u16* vgp = vp + (size_t)r*Sn + a*8;

  // swizzled read column offsets
  const int kg0 = ((    quad) ^ (ln & 7)) * 8;
  const int kg1 = ((4 + quad) ^ (ln & 7)) * 8;

  // prologue: K(0),V(0),K(1),V(1) issued; vmcnt(2) -> K0,V0 landed
  bf16x8 rvbuf[2];
  STGK(0, 0);
  rvbuf[0] = *(const bf16x8*)(vgp);
  STGK(1, 1);
  rvbuf[1] = *(const bf16x8*)(vgp + 64);
  VM2();
  {
    u16x4 lo = *(u16x4*)&rvbuf[0];
    u16x4 hi = *((u16x4*)&rvbuf[0] + 1);
    *(u16x4*)&Vs[0][vpos1] = lo;
    *(u16x4*)&Vs[0][vpos2] = hi;
  }
  WAIT_LGKM0();
  BARRAW();

  for (int ko = 0; ko < 8; ++ko){
    #pragma unroll
    for (int ku = 0; ku < 4; ++ku){
      const int kt = ko*4 + ku;

      // issue prefetch for tile kt+2 (K -> DMA, V -> regs)
      if (kt < 30){
        STGK((ku+2)&3, kt+2);
        rvbuf[ku&1] = *(const bf16x8*)(vgp + (kt+2)*64);
        SCHEDB();
      }

      const u16* Kc = Ks[ku & 3];   // == kt&3
      const u16* Vc = Vs[ku & 1];   // == kt&1

      #pragma unroll
      for (int ks = 0; ks < 2; ks++){
        f32x4 sacc[2][2] = {};
        #pragma unroll
        for (int kq = 0; kq < 2; kq++){
          const int kgo = kq ? kg1 : kg0;
          bf16x8 ka[2];
          #pragma unroll
          for (int m2 = 0; m2 < 2; m2++)
            ka[m2] = *(const bf16x8*)&Kc[((2*ks + m2)*16 + ln)*64 + kgo];
          __builtin_amdgcn_s_setprio(1);
          #pragma unroll
          for (int m2 = 0; m2 < 2; m2++)
            #pragma unroll
            for (int n = 0; n < 2; n++)
              sacc[m2][n] = __builtin_amdgcn_mfma_f32_16x16x32_bf16(ka[m2], qf[n][kq], sacc[m2][n], 0, 0, 0);
          __builtin_amdgcn_s_setprio(0);
        }
        B8 pb[2];
        #pragma unroll
        for (int n = 0; n < 2; n++){
          f32x4 s0 = sacc[0][n], s1 = sacc[1][n];
          float a0 = EXP2(s0[0]), a1 = EXP2(s0[1]), a2 = EXP2(s0[2]), a3 = EXP2(s0[3]);
          float b0 = EXP2(s1[0]), b1 = EXP2(s1[1]), b2 = EXP2(s1[2]), b3 = EXP2(s1[3]);
          dacc[n] += ((a0 + a1) + (a2 + a3)) + ((b0 + b1) + (b2 + b3));
          pb[n].u = (u32x4){pack_bf2(a0, a1), pack_bf2(a2, a3), pack_bf2(b0, b1), pack_bf2(b2, b3)};
        }
        const int vgo = ks ? kg1 : kg0;
        #pragma unroll
        for (int mtd = 0; mtd < 4; mtd++){
          bf16x8 va = *(const bf16x8*)&Vc[(mtd*16 + ln)*64 + vgo];
          __builtin_amdgcn_s_setprio(1);
          #pragma unroll
          for (int n = 0; n < 2; n++)
            zacc[mtd][n] = __builtin_amdgcn_mfma_f32_16x16x32_bf16(va, pb[n].s, zacc[mtd][n], 0, 0, 0);
          __builtin_amdgcn_s_setprio(0);
        }
      }

      // drain tile kt+1 (counted; K/V of kt+2 stay in flight), publish V(kt+1)
      if (kt < 31){
        if (kt < 30) { VM2(); } else { VM0(); }
        u16x4 lo = *(u16x4*)&rvbuf[(ku+1)&1];
        u16x4 hi = *((u16x4*)&rvbuf[(ku+1)&1] + 1);
        *(u16x4*)&Vs[(ku+1)&1][vpos1] = lo;
        *(u16x4*)&Vs[(ku+1)&1][vpos2] = hi;
        WAIT_LGKM0();
        BARRAW();
      }
    }
  }
#undef STGK

  float inv[2];
  #pragma unroll
  for (int n = 0; n < 2; n++){
    float d = dacc[n];
    d += __shfl_xor(d, 16, 64);
    d += __shfl_xor(d, 32, 64);
    inv[n] = 1.0f / d;
  }

  #pragma unroll
  for (int mtd = 0; mtd < 4; mtd++)
    #pragma unroll
    for (int n = 0; n < 2; n++){
      u16x4 o;
      #pragma unroll
      for (int j = 0; j < 4; j++) o[j] = f2bf(zacc[mtd][n][j] * inv[n]);
      *(u16x4*)(z + (bh*Sn + (size_t)(q0 + n*16 + ln))*DHn + mtd*16 + quad*4) = o;
    }
}

// ---------------- out = z * Wout^T + x: same A-tri/B-dbuf template, K-chunk 64 == head ----------------
__launch_bounds__(256)
__global__ void gemm_out_kernel(const u16* __restrict__ zb, const u16* __restrict__ wt,
                                const float* __restrict__ x, float* __restrict__ out){
  __shared__ u16 sm[40960];   // 80 KB
  const int t = threadIdx.x;
  const int lane = t & 63, wave = t >> 6;
  const int ln = lane & 15, quad = lane >> 4;
  const int wm = wave >> 1, wn = wave & 1;

  const int lin = blockIdx.x;
  const int wg = (lin & 7) * 64 + (lin >> 3);
  const int m0 = (wg >> 3) * 128;
  const int n0 = (wg & 7) * 128;

  const u16* ap[4]; const u16* bp[4]; int ldo[4];
  #pragma unroll
  for (int p = 0; p < 4; p++){
    int idx = p*256 + t;
    int r = idx >> 3, g = (idx & 7) ^ (r & 7);
    int row = m0 + r, bb = row >> 11, s = row & 2047;
    ap[p] = zb + ((size_t)bb*Hn*Sn + s)*DHn + g*8;    // head-0 base; head stride Sn*DHn
    bp[p] = wt + (size_t)(n0 + r)*Dn + g*8;
    ldo[p] = idx * 8;
  }
#define STGA(buf, tt) do { _Pragma("unroll") for (int p = 0; p < 4; p++) \
    G2L16(&sm[(buf) + ldo[p]], ap[p] + (size_t)(tt)*Sn*DHn); } while(0)
#define STGB(buf, tt) do { _Pragma("unroll") for (int p = 0; p < 4; p++) \
    G2L16(&sm[(buf) + ldo[p]], bp[p] + (size_t)(tt)*64); } while(0)

  const int agr0 = ((    quad) ^ (ln & 7)) * 8;
  const int agr1 = ((4 + quad) ^ (ln & 7)) * 8;
  int arow[4], brow[4];
  #pragma unroll
  for (int i = 0; i < 4; i++) arow[i] = (wm*64 + i*16 + ln) * 64;
  #pragma unroll
  for (int j = 0; j < 4; j++) brow[j] = (wn*64 + j*16 + ln) * 64;

  f32x4 acc[4][4] = {};
  STGA(0, 0); STGB(24576, 0); STGA(8192, 1);

  #pragma unroll
  for (int tt = 0; tt < 16; ++tt){
    const int a_cur = (tt % 3) * 8192;
    const int a_pf  = ((tt + 2) % 3) * 8192;
    const int b_cur = 24576 + (tt & 1) * 8192;
    const int b_pf  = 24576 + ((tt + 1) & 1) * 8192;

    if (tt < 15) { VM4(); } else { VM0(); }
    BARRAW(); SCHEDB();

    bf16x8 a01[2][2], bq[4][2];
    #pragma unroll
    for (int i = 0; i < 2; i++){
      a01[i][0] = *(const bf16x8*)&sm[a_cur + arow[i] + agr0];
      a01[i][1] = *(const bf16x8*)&sm[a_cur + arow[i] + agr1];
    }
    #pragma unroll
    for (int j = 0; j < 4; j++){
      bq[j][0] = *(const bf16x8*)&sm[b_cur + brow[j] + agr0];
      bq[j][1] = *(const bf16x8*)&sm[b_cur + brow[j] + agr1];
    }
    SCHEDB();
    if (tt < 15) STGB(b_pf, tt + 1);
    SCHEDB();
    WAIT_LGKM0(); SCHEDB();
    __builtin_amdgcn_s_setprio(1);
    #pragma unroll
    for (int i = 0; i < 2; i++)
      #pragma unroll
      for (int j = 0; j < 4; j++){
        MFMA_B16(acc[i][j], a01[i][0], bq[j][0]);
        MFMA_B16(acc[i][j], a01[i][1], bq[j][1]);
      }
    __builtin_amdgcn_s_setprio(0);

    bf16x8 a23[2][2];
    #pragma unroll
    for (int i = 0; i < 2; i++){
      a23[i][0] = *(const bf16x8*)&sm[a_cur + arow[2+i] + agr0];
      a23[i][1] = *(const bf16x8*)&sm[a_cur + arow[2+i] + agr1];
    }
    SCHEDB();
    if (tt < 14) STGA(a_pf, tt + 2);
    SCHEDB();
    WAIT_LGKM0(); SCHEDB();
    __builtin_amdgcn_s_setprio(1);
    #pragma unroll
    for (int i = 0; i < 2; i++)
      #pragma unroll
      for (int j = 0; j < 4; j++){
        MFMA_B16(acc[2+i][j], a23[i][0], bq[j][0]);
        MFMA_B16(acc[2+i][j], a23[i][1], bq[j][1]);
      }
    __builtin_amdgcn_s_setprio(0);
  }

  #pragma unroll
  for (int rb = 0; rb < 4; rb++)
    #pragma unroll
    for (int cb = 0; cb < 4; cb++)
      #pragma unroll
      for (int reg = 0; reg < 4; reg++){
        int row = m0 + wm*64 + rb*16 + quad*4 + reg;
        int col = n0 + wn*64 + cb*16 + ln;
        size_t off = (size_t)row*Dn + col;
        out[off] = acc[rb][cb][reg] + x[off];
      }
#undef STGA
#undef STGB
}

extern "C" void kernel_launch(void* const* d_in, const int* in_sizes, int n_in,
                              void* d_out, int out_size, void* d_ws, size_t ws_size,
                              hipStream_t stream){
  const float* x    = (const float*)d_in[0];
  const float* Wq   = (const float*)d_in[2];
  const float* Wk   = (const float*)d_in[3];
  const float* Wv   = (const float*)d_in[4];
  const float* Wout = (const float*)d_in[5];
  float* out = (float*)d_out;

  u16* ws = (u16*)d_ws;
  const size_t NW = (size_t)Dn * Dn;
  const size_t NX = (size_t)Bn * Sn * Dn;
  u16* wt  = ws;                // Wq^T(scaled),Wk^T,Wv^T,Wout^T
  u16* xb  = wt + 4*NW;         // x bf16
  u16* qb  = xb + NX;           // Q [b,h,s,d] (attn writes z in-place)
  u16* kb  = qb + NX;           // K [b,h,s,d]
  u16* vtb = kb + NX;           // Vt [b,h,d,s] (written directly by gemm_qkv)

  prep_kernel     <<<dim3(4096 + 1024), dim3(256), 0, stream>>>(x, Wq, Wk, Wv, Wout, xb, wt);
  gemm_qkv_kernel <<<dim3(1536), dim3(256), 0, stream>>>(xb, wt, qb, kb, vtb);
  attn_kernel     <<<dim3(8,16,4), dim3(512), 0, stream>>>(qb, kb, vtb, qb);
  gemm_out_kernel <<<dim3(512), dim3(256), 0, stream>>>(qb, wt + 3*NW, x, out);
}

// Round 5
// 436.298 us; speedup vs baseline: 1.3020x; 1.3020x over previous
//
#include <hip/hip_runtime.h>

#define Bn 4
#define Sn 2048
#define Dn 1024
#define Hn 16
#define DHn 64

typedef float f32x4 __attribute__((ext_vector_type(4)));
typedef short bf16x8 __attribute__((ext_vector_type(8)));
typedef unsigned short u16;
typedef unsigned int u32;
typedef unsigned short u16x8 __attribute__((ext_vector_type(8)));
typedef unsigned short u16x4 __attribute__((ext_vector_type(4)));
typedef u32 u32x4 __attribute__((ext_vector_type(4)));

union B8 { u32x4 u; bf16x8 s; u16x8 h; };

__device__ __forceinline__ u16 f2bf(float f){
  union { float f; u32 u; } v; v.f = f;
  return (u16)((v.u + 0x7fffu + ((v.u >> 16) & 1u)) >> 16);
}

// truncating pack: two fp32 -> {bf16(lo) | bf16(hi)<<16}. P>0 -> -0.2% uniform bias, negligible.
__device__ __forceinline__ u32 pack_bf2(float lo, float hi){
  union { float f; u32 u; } a, b;
  a.f = lo; b.f = hi;
  return __builtin_amdgcn_perm(b.u, a.u, 0x07060302u);
}

#if __has_builtin(__builtin_amdgcn_exp2f)
#define EXP2(x) __builtin_amdgcn_exp2f(x)
#define QSCALE 0.18033688011112042f   /* 0.125 * log2(e) */
#else
#define EXP2(x) __expf(x)
#define QSCALE 0.125f
#endif

#if __has_builtin(__builtin_amdgcn_global_load_lds)
#define G2L16(l, g) __builtin_amdgcn_global_load_lds((const __attribute__((address_space(1))) u32*)(g), \
                                                     (__attribute__((address_space(3))) u32*)(l), 16, 0, 0)
#else
#define G2L16(l, g) (*(bf16x8*)(l) = *(const bf16x8*)(g))
#endif

#define MFMA_B16(d, va, vb) (d) = __builtin_amdgcn_mfma_f32_16x16x32_bf16((va), (vb), (d), 0, 0, 0)
#define BARRAW() __builtin_amdgcn_s_barrier()
#define WAIT_LGKM0() asm volatile("s_waitcnt lgkmcnt(0)" ::: "memory")
#define VM4() asm volatile("s_waitcnt vmcnt(4)" ::: "memory")
#define VM0() asm volatile("s_waitcnt vmcnt(0)" ::: "memory")
#define SCHEDB() __builtin_amdgcn_sched_barrier(0)

// ---------------- merged prep: cast x (blocks 0..4095) + 4 weights (4096..5119) ----------------
__global__ void prep_kernel(const float* __restrict__ x,
                            const float* __restrict__ Wq, const float* __restrict__ Wk,
                            const float* __restrict__ Wv, const float* __restrict__ Wo,
                            u16* __restrict__ xb, u16* __restrict__ wt_all){
  __shared__ u16 tile[64*66];
  const int t = threadIdx.x;
  if (blockIdx.x < 4096){
    size_t i = ((size_t)blockIdx.x * 256 + t) * 8;
    float4 f0 = *(const float4*)(x + i);
    float4 f1 = *(const float4*)(x + i + 4);
    u16x8 o;
    o[0]=f2bf(f0.x); o[1]=f2bf(f0.y); o[2]=f2bf(f0.z); o[3]=f2bf(f0.w);
    o[4]=f2bf(f1.x); o[5]=f2bf(f1.y); o[6]=f2bf(f1.z); o[7]=f2bf(f1.w);
    *(u16x8*)(xb + i) = o;
    return;
  }
  const int wi = blockIdx.x - 4096;
  const int z = wi >> 8, r8 = wi & 255;
  const int k0 = (r8 >> 4) * 64, n0 = (r8 & 15) * 64;
  const float* w = (z == 0) ? Wq : (z == 1) ? Wk : (z == 2) ? Wv : Wo;
  const float scale = (z == 0) ? QSCALE : 1.0f;
  u16* wt = wt_all + (size_t)z * Dn * Dn;
  #pragma unroll
  for (int i = 0; i < 4; i++){
    int idx = i*256 + t;
    int r = idx >> 4, c4 = (idx & 15) * 4;
    float4 f = *(const float4*)(w + (size_t)(k0 + r)*Dn + n0 + c4);
    tile[r*66 + c4 + 0] = f2bf(f.x * scale);
    tile[r*66 + c4 + 1] = f2bf(f.y * scale);
    tile[r*66 + c4 + 2] = f2bf(f.z * scale);
    tile[r*66 + c4 + 3] = f2bf(f.w * scale);
  }
  __syncthreads();
  #pragma unroll
  for (int i = 0; i < 4; i++){
    int idx = i*256 + t;
    int nr = idx >> 4, kc4 = (idx & 15) * 4;
    u16x4 o;
    o[0] = tile[(kc4+0)*66 + nr];
    o[1] = tile[(kc4+1)*66 + nr];
    o[2] = tile[(kc4+2)*66 + nr];
    o[3] = tile[(kc4+3)*66 + nr];
    *(u16x4*)(wt + (size_t)(n0 + nr)*Dn + k0 + kc4) = o;
  }
}

// ---------------- QKV GEMM: 128^2 tile, BK=64, A-tri/B-dbuf, 1 barrier/K-tile ----------------
__launch_bounds__(256)
__global__ void gemm_qkv_kernel(const u16* __restrict__ xb, const u16* __restrict__ wt_all,
                                u16* __restrict__ qb, u16* __restrict__ kb, u16* __restrict__ vtb){
  __shared__ u16 sm[40960];   // 80 KB
  const int t = threadIdx.x;
  const int lane = t & 63, wave = t >> 6;
  const int ln = lane & 15, quad = lane >> 4;
  const int wm = wave >> 1, wn = wave & 1;

  // T1: XCD-chunked bijective swizzle (1536 = 8*192), m-outer n-inner within chunk
  const int lin = blockIdx.x;
  const int wg = (lin & 7) * 192 + (lin >> 3);
  const int zsel = wg >> 9;
  const int rem = wg & 511;
  const int m0 = (rem >> 3) * 128;
  const int n0 = (rem & 7) * 128;
  const u16* wt = wt_all + (size_t)zsel * Dn * Dn;

  const u16* ap[4]; const u16* bp[4]; int ldo[4];
  #pragma unroll
  for (int p = 0; p < 4; p++){
    int idx = p*256 + t;
    int r = idx >> 3, g = (idx & 7) ^ (r & 7);
    ap[p] = xb + (size_t)(m0 + r)*Dn + g*8;
    bp[p] = wt + (size_t)(n0 + r)*Dn + g*8;
    ldo[p] = idx * 8;
  }
#define STGA(buf, tt) do { _Pragma("unroll") for (int p = 0; p < 4; p++) \
    G2L16(&sm[(buf) + ldo[p]], ap[p] + (size_t)(tt)*64); } while(0)
#define STGB(buf, tt) do { _Pragma("unroll") for (int p = 0; p < 4; p++) \
    G2L16(&sm[(buf) + ldo[p]], bp[p] + (size_t)(tt)*64); } while(0)

  const int agr0 = ((    quad) ^ (ln & 7)) * 8;
  const int agr1 = ((4 + quad) ^ (ln & 7)) * 8;
  int arow[4], brow[4];
  #pragma unroll
  for (int i = 0; i < 4; i++) arow[i] = (wm*64 + i*16 + ln) * 64;
  #pragma unroll
  for (int j = 0; j < 4; j++) brow[j] = (wn*64 + j*16 + ln) * 64;

  f32x4 acc[4][4] = {};

  STGA(0, 0); STGB(24576, 0); STGA(8192, 1);

  #pragma unroll
  for (int tt = 0; tt < 16; ++tt){
    const int a_cur = (tt % 3) * 8192;
    const int a_pf  = ((tt + 2) % 3) * 8192;
    const int b_cur = 24576 + (tt & 1) * 8192;
    const int b_pf  = 24576 + ((tt + 1) & 1) * 8192;

    if (tt < 15) { VM4(); } else { VM0(); }
    BARRAW(); SCHEDB();

    bf16x8 a01[2][2], bq[4][2];
    #pragma unroll
    for (int i = 0; i < 2; i++){
      a01[i][0] = *(const bf16x8*)&sm[a_cur + arow[i] + agr0];
      a01[i][1] = *(const bf16x8*)&sm[a_cur + arow[i] + agr1];
    }
    #pragma unroll
    for (int j = 0; j < 4; j++){
      bq[j][0] = *(const bf16x8*)&sm[b_cur + brow[j] + agr0];
      bq[j][1] = *(const bf16x8*)&sm[b_cur + brow[j] + agr1];
    }
    SCHEDB();
    if (tt < 15) STGB(b_pf, tt + 1);
    SCHEDB();
    WAIT_LGKM0(); SCHEDB();
    __builtin_amdgcn_s_setprio(1);
    #pragma unroll
    for (int i = 0; i < 2; i++)
      #pragma unroll
      for (int j = 0; j < 4; j++){
        MFMA_B16(acc[i][j], a01[i][0], bq[j][0]);
        MFMA_B16(acc[i][j], a01[i][1], bq[j][1]);
      }
    __builtin_amdgcn_s_setprio(0);

    bf16x8 a23[2][2];
    #pragma unroll
    for (int i = 0; i < 2; i++){
      a23[i][0] = *(const bf16x8*)&sm[a_cur + arow[2+i] + agr0];
      a23[i][1] = *(const bf16x8*)&sm[a_cur + arow[2+i] + agr1];
    }
    SCHEDB();
    if (tt < 14) STGA(a_pf, tt + 2);
    SCHEDB();
    WAIT_LGKM0(); SCHEDB();
    __builtin_amdgcn_s_setprio(1);
    #pragma unroll
    for (int i = 0; i < 2; i++)
      #pragma unroll
      for (int j = 0; j < 4; j++){
        MFMA_B16(acc[2+i][j], a23[i][0], bq[j][0]);
        MFMA_B16(acc[2+i][j], a23[i][1], bq[j][1]);
      }
    __builtin_amdgcn_s_setprio(0);
  }

  __syncthreads();
  u16* Cs = sm;
  if (zsel < 2){
    u16* outp = (zsel == 0) ? qb : kb;
    #pragma unroll
    for (int rb = 0; rb < 4; rb++)
      #pragma unroll
      for (int cb = 0; cb < 4; cb++)
        #pragma unroll
        for (int reg = 0; reg < 4; reg++)
          Cs[(wm*64 + rb*16 + quad*4 + reg)*136 + wn*64 + cb*16 + ln] = f2bf(acc[rb][cb][reg]);
    __syncthreads();
    #pragma unroll
    for (int i = 0; i < 8; i++){
      int idx = i*256 + t;
      int r = idx >> 4, c8 = (idx & 15) * 8;
      bf16x8 vdat = *(const bf16x8*)&Cs[r*136 + c8];
      int row = m0 + r, bb = row >> 11, s = row & 2047;
      int col = n0 + c8, hh = col >> 6, d = col & 63;
      *(bf16x8*)(outp + (((size_t)bb*Hn + hh)*Sn + s)*DHn + d) = vdat;
    }
  } else {
    #pragma unroll
    for (int rb = 0; rb < 4; rb++)
      #pragma unroll
      for (int cb = 0; cb < 4; cb++){
        u16x4 o;
        #pragma unroll
        for (int reg = 0; reg < 4; reg++) o[reg] = f2bf(acc[rb][cb][reg]);
        *(u16x4*)&Cs[(wn*64 + cb*16 + ln)*136 + wm*64 + rb*16 + quad*4] = o;
      }
    __syncthreads();
    #pragma unroll
    for (int i = 0; i < 8; i++){
      int idx = i*256 + t;
      int c = idx >> 4, r8 = (idx & 15) * 8;
      bf16x8 vdat = *(const bf16x8*)&Cs[c*136 + r8];
      int col = n0 + c, hh = col >> 6, d = col & 63;
      int row = m0 + r8, bb = row >> 11, s = row & 2047;
      *(bf16x8*)(vtb + (((size_t)bb*Hn + hh)*DHn + d)*Sn + s) = vdat;
    }
  }
#undef STGA
#undef STGB
}

// ---------------- attention: 8 waves x 32 q, pair-phase pipeline (1 barrier / 2 tiles) ----------------
// K: 4-deep LDS slots via global_load_lds (pre-swizzled per-lane source, linear dest).
// V: 4-deep LDS slots; pair loaded to regs at phase top, ds_written (col-shuffle+swizzle)
//    at phase end after vmcnt(0). One raw s_barrier per 2 tiles (16 total vs 32):
//    the 2-tile barrier-free window lets waves drift so MFMA and VALU/exp phases of
//    different waves overlap (breaks the per-tile phase-lock that pinned 77us).
// Per-tile compute body is bit-identical to the r3 version (same op order).
__launch_bounds__(512, 4)
__global__ void attn_kernel(const u16* q, const u16* __restrict__ k,
                            const u16* __restrict__ vt, u16* z){
  __shared__ u16 Ks[4][64*64];   // [key][d], swizzled granules
  __shared__ u16 Vs[4][64*64];   // [d][key'] column-shuffled + swizzled
  const int t = threadIdx.x;
  const int wave = t >> 6, lane = t & 63;
  const int ln = lane & 15, quad = lane >> 4;
  const int lin = blockIdx.x + 8*(blockIdx.y + 16*blockIdx.z);
  const int wgs = (lin & 7)*64 + (lin >> 3);
  const int qt = wgs & 7, h = (wgs >> 3) & 15, b = wgs >> 7;
  const size_t bh = (size_t)b * Hn + h;
  const int q0 = qt*256 + wave*32;
  const u16* qp = q + bh * Sn * DHn;
  const u16* kp = k + bh * Sn * DHn;
  const u16* vp = vt + bh * DHn * Sn;

  bf16x8 qf[2][2];
  #pragma unroll
  for (int n = 0; n < 2; n++)
    #pragma unroll
    for (int kq = 0; kq < 2; kq++)
      qf[n][kq] = *(const bf16x8*)(qp + (size_t)(q0 + n*16 + ln)*DHn + kq*32 + quad*8);

  f32x4 zacc[4][2] = {};
  float dacc[2] = {0.f, 0.f};

  // staging coords: thread t handles granule a of row r (512 thr = 64x8 granules)
  const int r = t >> 3, a = t & 7;
  const u16* kgp = kp + (size_t)r*DHn + ((a ^ (r & 7)) * 8);
  const int kldo = t * 8;
#define STGK(slot, tt) G2L16(&Ks[slot][kldo], kgp + (size_t)(tt)*4096)
  const int ksg = a >> 2, q1 = ((a&3)*2)&3, h1 = (a&3) >> 1;
  const int vc1 = ksg*32 + q1*8 + h1*4;
  const int vc2 = ksg*32 + (((q1+1)&3))*8 + h1*4;
  const int vpos1 = r*64 + ((vc1>>3) ^ (r&7))*8 + (vc1 & 7);
  const int vpos2 = r*64 + ((vc2>>3) ^ (r&7))*8 + (vc2 & 7);
  const u16* vgp = vp + (size_t)r*Sn + a*8;
#define WRV(slot, rv) do { \
    u16x4 lo_ = *(u16x4*)&(rv); \
    u16x4 hi_ = *((u16x4*)&(rv) + 1); \
    *(u16x4*)&Vs[slot][vpos1] = lo_; \
    *(u16x4*)&Vs[slot][vpos2] = hi_; } while(0)

  // swizzled read column offsets
  const int kg0 = ((    quad) ^ (ln & 7)) * 8;
  const int kg1 = ((4 + quad) ^ (ln & 7)) * 8;

#define TILE_COMPUTE(slot) do { \
    const u16* Kc = Ks[slot]; \
    const u16* Vc = Vs[slot]; \
    _Pragma("unroll") \
    for (int ks = 0; ks < 2; ks++){ \
      f32x4 sacc[2][2] = {}; \
      _Pragma("unroll") \
      for (int kq = 0; kq < 2; kq++){ \
        const int kgo = kq ? kg1 : kg0; \
        bf16x8 ka[2]; \
        _Pragma("unroll") \
        for (int m2 = 0; m2 < 2; m2++) \
          ka[m2] = *(const bf16x8*)&Kc[((2*ks + m2)*16 + ln)*64 + kgo]; \
        __builtin_amdgcn_s_setprio(1); \
        _Pragma("unroll") \
        for (int m2 = 0; m2 < 2; m2++) \
          _Pragma("unroll") \
          for (int n = 0; n < 2; n++) \
            sacc[m2][n] = __builtin_amdgcn_mfma_f32_16x16x32_bf16(ka[m2], qf[n][kq], sacc[m2][n], 0, 0, 0); \
        __builtin_amdgcn_s_setprio(0); \
      } \
      B8 pb[2]; \
      _Pragma("unroll") \
      for (int n = 0; n < 2; n++){ \
        f32x4 s0 = sacc[0][n], s1 = sacc[1][n]; \
        float a0 = EXP2(s0[0]), a1 = EXP2(s0[1]), a2 = EXP2(s0[2]), a3 = EXP2(s0[3]); \
        float b0 = EXP2(s1[0]), b1 = EXP2(s1[1]), b2 = EXP2(s1[2]), b3 = EXP2(s1[3]); \
        dacc[n] += ((a0 + a1) + (a2 + a3)) + ((b0 + b1) + (b2 + b3)); \
        pb[n].u = (u32x4){pack_bf2(a0, a1), pack_bf2(a2, a3), pack_bf2(b0, b1), pack_bf2(b2, b3)}; \
      } \
      const int vgo = ks ? kg1 : kg0; \
      _Pragma("unroll") \
      for (int mtd = 0; mtd < 4; mtd++){ \
        bf16x8 va = *(const bf16x8*)&Vc[(mtd*16 + ln)*64 + vgo]; \
        __builtin_amdgcn_s_setprio(1); \
        _Pragma("unroll") \
        for (int n = 0; n < 2; n++) \
          zacc[mtd][n] = __builtin_amdgcn_mfma_f32_16x16x32_bf16(va, pb[n].s, zacc[mtd][n], 0, 0, 0); \
        __builtin_amdgcn_s_setprio(0); \
      } \
    } \
  } while(0)

  bf16x8 rv0, rv1;

  // prologue: stage tiles 0,1 into slots 0,1
  STGK(0, 0); STGK(1, 1);
  rv0 = *(const bf16x8*)(vgp);
  rv1 = *(const bf16x8*)(vgp + 64);
  VM0();
  WRV(0, rv0); WRV(1, rv1);
  WAIT_LGKM0();
  BARRAW();

  for (int p2 = 0; p2 < 8; ++p2){
    // ---- phase A: compute slots {0,1} (tiles 4p2, 4p2+1); stage tiles +2,+3 -> slots {2,3}
    {
      const int T = 4*p2;
      STGK(2, T+2); STGK(3, T+3);
      rv0 = *(const bf16x8*)(vgp + (size_t)(T+2)*64);
      rv1 = *(const bf16x8*)(vgp + (size_t)(T+3)*64);
      SCHEDB();
      TILE_COMPUTE(0);
      TILE_COMPUTE(1);
      VM0();
      WRV(2, rv0); WRV(3, rv1);
      WAIT_LGKM0();
      BARRAW();
    }
    // ---- phase B: compute slots {2,3} (tiles 4p2+2, 4p2+3); stage tiles +4,+5 -> slots {0,1}
    {
      const int T = 4*p2 + 2;
      if (T + 2 < 32){
        STGK(0, T+2); STGK(1, T+3);
        rv0 = *(const bf16x8*)(vgp + (size_t)(T+2)*64);
        rv1 = *(const bf16x8*)(vgp + (size_t)(T+3)*64);
        SCHEDB();
      }
      TILE_COMPUTE(2);
      TILE_COMPUTE(3);
      if (T + 2 < 32){
        VM0();
        WRV(0, rv0); WRV(1, rv1);
        WAIT_LGKM0();
        BARRAW();
      }
    }
  }
#undef STGK
#undef WRV
#undef TILE_COMPUTE

  float inv[2];
  #pragma unroll
  for (int n = 0; n < 2; n++){
    float d = dacc[n];
    d += __shfl_xor(d, 16, 64);
    d += __shfl_xor(d, 32, 64);
    inv[n] = 1.0f / d;
  }

  #pragma unroll
  for (int mtd = 0; mtd < 4; mtd++)
    #pragma unroll
    for (int n = 0; n < 2; n++){
      u16x4 o;
      #pragma unroll
      for (int j = 0; j < 4; j++) o[j] = f2bf(zacc[mtd][n][j] * inv[n]);
      *(u16x4*)(z + (bh*Sn + (size_t)(q0 + n*16 + ln))*DHn + mtd*16 + quad*4) = o;
    }
}

// ---------------- out = z * Wout^T + x: same A-tri/B-dbuf template, K-chunk 64 == head ----------------
__launch_bounds__(256)
__global__ void gemm_out_kernel(const u16* __restrict__ zb, const u16* __restrict__ wt,
                                const float* __restrict__ x, float* __restrict__ out){
  __shared__ u16 sm[40960];   // 80 KB
  const int t = threadIdx.x;
  const int lane = t & 63, wave = t >> 6;
  const int ln = lane & 15, quad = lane >> 4;
  const int wm = wave >> 1, wn = wave & 1;

  const int lin = blockIdx.x;
  const int wg = (lin & 7) * 64 + (lin >> 3);
  const int m0 = (wg >> 3) * 128;
  const int n0 = (wg & 7) * 128;

  const u16* ap[4]; const u16* bp[4]; int ldo[4];
  #pragma unroll
  for (int p = 0; p < 4; p++){
    int idx = p*256 + t;
    int r = idx >> 3, g = (idx & 7) ^ (r & 7);
    int row = m0 + r, bb = row >> 11, s = row & 2047;
    ap[p] = zb + ((size_t)bb*Hn*Sn + s)*DHn + g*8;    // head-0 base; head stride Sn*DHn
    bp[p] = wt + (size_t)(n0 + r)*Dn + g*8;
    ldo[p] = idx * 8;
  }
#define STGA(buf, tt) do { _Pragma("unroll") for (int p = 0; p < 4; p++) \
    G2L16(&sm[(buf) + ldo[p]], ap[p] + (size_t)(tt)*Sn*DHn); } while(0)
#define STGB(buf, tt) do { _Pragma("unroll") for (int p = 0; p < 4; p++) \
    G2L16(&sm[(buf) + ldo[p]], bp[p] + (size_t)(tt)*64); } while(0)

  const int agr0 = ((    quad) ^ (ln & 7)) * 8;
  const int agr1 = ((4 + quad) ^ (ln & 7)) * 8;
  int arow[4], brow[4];
  #pragma unroll
  for (int i = 0; i < 4; i++) arow[i] = (wm*64 + i*16 + ln) * 64;
  #pragma unroll
  for (int j = 0; j < 4; j++) brow[j] = (wn*64 + j*16 + ln) * 64;

  f32x4 acc[4][4] = {};
  STGA(0, 0); STGB(24576, 0); STGA(8192, 1);

  #pragma unroll
  for (int tt = 0; tt < 16; ++tt){
    const int a_cur = (tt % 3) * 8192;
    const int a_pf  = ((tt + 2) % 3) * 8192;
    const int b_cur = 24576 + (tt & 1) * 8192;
    const int b_pf  = 24576 + ((tt + 1) & 1) * 8192;

    if (tt < 15) { VM4(); } else { VM0(); }
    BARRAW(); SCHEDB();

    bf16x8 a01[2][2], bq[4][2];
    #pragma unroll
    for (int i = 0; i < 2; i++){
      a01[i][0] = *(const bf16x8*)&sm[a_cur + arow[i] + agr0];
      a01[i][1] = *(const bf16x8*)&sm[a_cur + arow[i] + agr1];
    }
    #pragma unroll
    for (int j = 0; j < 4; j++){
      bq[j][0] = *(const bf16x8*)&sm[b_cur + brow[j] + agr0];
      bq[j][1] = *(const bf16x8*)&sm[b_cur + brow[j] + agr1];
    }
    SCHEDB();
    if (tt < 15) STGB(b_pf, tt + 1);
    SCHEDB();
    WAIT_LGKM0(); SCHEDB();
    __builtin_amdgcn_s_setprio(1);
    #pragma unroll
    for (int i = 0; i < 2; i++)
      #pragma unroll
      for (int j = 0; j < 4; j++){
        MFMA_B16(acc[i][j], a01[i][0], bq[j][0]);
        MFMA_B16(acc[i][j], a01[i][1], bq[j][1]);
      }
    __builtin_amdgcn_s_setprio(0);

    bf16x8 a23[2][2];
    #pragma unroll
    for (int i = 0; i < 2; i++){
      a23[i][0] = *(const bf16x8*)&sm[a_cur + arow[2+i] + agr0];
      a23[i][1] = *(const bf16x8*)&sm[a_cur + arow[2+i] + agr1];
    }
    SCHEDB();
    if (tt < 14) STGA(a_pf, tt + 2);
    SCHEDB();
    WAIT_LGKM0(); SCHEDB();
    __builtin_amdgcn_s_setprio(1);
    #pragma unroll
    for (int i = 0; i < 2; i++)
      #pragma unroll
      for (int j = 0; j < 4; j++){
        MFMA_B16(acc[2+i][j], a23[i][0], bq[j][0]);
        MFMA_B16(acc[2+i][j], a23[i][1], bq[j][1]);
      }
    __builtin_amdgcn_s_setprio(0);
  }

  #pragma unroll
  for (int rb = 0; rb < 4; rb++)
    #pragma unroll
    for (int cb = 0; cb < 4; cb++)
      #pragma unroll
      for (int reg = 0; reg < 4; reg++){
        int row = m0 + wm*64 + rb*16 + quad*4 + reg;
        int col = n0 + wn*64 + cb*16 + ln;
        size_t off = (size_t)row*Dn + col;
        out[off] = acc[rb][cb][reg] + x[off];
      }
#undef STGA
#undef STGB
}

extern "C" void kernel_launch(void* const* d_in, const int* in_sizes, int n_in,
                              void* d_out, int out_size, void* d_ws, size_t ws_size,
                              hipStream_t stream){
  const float* x    = (const float*)d_in[0];
  const float* Wq   = (const float*)d_in[2];
  const float* Wk   = (const float*)d_in[3];
  const float* Wv   = (const float*)d_in[4];
  const float* Wout = (const float*)d_in[5];
  float* out = (float*)d_out;

  u16* ws = (u16*)d_ws;
  const size_t NW = (size_t)Dn * Dn;
  const size_t NX = (size_t)Bn * Sn * Dn;
  u16* wt  = ws;                // Wq^T(scaled),Wk^T,Wv^T,Wout^T
  u16* xb  = wt + 4*NW;         // x bf16
  u16* qb  = xb + NX;           // Q [b,h,s,d] (attn writes z in-place)
  u16* kb  = qb + NX;           // K [b,h,s,d]
  u16* vtb = kb + NX;           // Vt [b,h,d,s] (written directly by gemm_qkv)

  prep_kernel     <<<dim3(4096 + 1024), dim3(256), 0, stream>>>(x, Wq, Wk, Wv, Wout, xb, wt);
  gemm_qkv_kernel <<<dim3(1536), dim3(256), 0, stream>>>(xb, wt, qb, kb, vtb);
  attn_kernel     <<<dim3(8,16,4), dim3(512), 0, stream>>>(qb, kb, vtb, qb);
  gemm_out_kernel <<<dim3(512), dim3(256), 0, stream>>>(qb, wt + 3*NW, x, out);
}

// Round 6
// 291.376 us; speedup vs baseline: 1.9495x; 1.4974x over previous
//
#include <hip/hip_runtime.h>

#define Bn 4
#define Sn 2048
#define Dn 1024
#define Hn 16
#define DHn 64

typedef float f32x4 __attribute__((ext_vector_type(4)));
typedef short bf16x8 __attribute__((ext_vector_type(8)));
typedef unsigned short u16;
typedef unsigned int u32;
typedef unsigned short u16x8 __attribute__((ext_vector_type(8)));
typedef unsigned short u16x4 __attribute__((ext_vector_type(4)));
typedef u32 u32x4 __attribute__((ext_vector_type(4)));

union B8 { u32x4 u; bf16x8 s; u16x8 h; };

__device__ __forceinline__ u16 f2bf(float f){
  union { float f; u32 u; } v; v.f = f;
  return (u16)((v.u + 0x7fffu + ((v.u >> 16) & 1u)) >> 16);
}

// truncating pack: two fp32 -> {bf16(lo) | bf16(hi)<<16}. P>0 -> -0.2% uniform bias, negligible.
__device__ __forceinline__ u32 pack_bf2(float lo, float hi){
  union { float f; u32 u; } a, b;
  a.f = lo; b.f = hi;
  return __builtin_amdgcn_perm(b.u, a.u, 0x07060302u);
}

#if __has_builtin(__builtin_amdgcn_exp2f)
#define EXP2(x) __builtin_amdgcn_exp2f(x)
#define QSCALE 0.18033688011112042f   /* 0.125 * log2(e) */
#else
#define EXP2(x) __expf(x)
#define QSCALE 0.125f
#endif

#if __has_builtin(__builtin_amdgcn_global_load_lds)
#define G2L16(l, g) __builtin_amdgcn_global_load_lds((const __attribute__((address_space(1))) u32*)(g), \
                                                     (__attribute__((address_space(3))) u32*)(l), 16, 0, 0)
#else
#define G2L16(l, g) (*(bf16x8*)(l) = *(const bf16x8*)(g))
#endif

#define MFMA_B16(d, va, vb) (d) = __builtin_amdgcn_mfma_f32_16x16x32_bf16((va), (vb), (d), 0, 0, 0)
#define BARRAW() __builtin_amdgcn_s_barrier()
#define WAIT_LGKM0() asm volatile("s_waitcnt lgkmcnt(0)" ::: "memory")
#define VM4() asm volatile("s_waitcnt vmcnt(4)" ::: "memory")
#define VM0() asm volatile("s_waitcnt vmcnt(0)" ::: "memory")
#define SCHEDB() __builtin_amdgcn_sched_barrier(0)

// ---------------- merged prep: cast x (blocks 0..4095) + 4 weights (4096..5119) ----------------
__global__ void prep_kernel(const float* __restrict__ x,
                            const float* __restrict__ Wq, const float* __restrict__ Wk,
                            const float* __restrict__ Wv, const float* __restrict__ Wo,
                            u16* __restrict__ xb, u16* __restrict__ wt_all){
  __shared__ u16 tile[64*66];
  const int t = threadIdx.x;
  if (blockIdx.x < 4096){
    size_t i = ((size_t)blockIdx.x * 256 + t) * 8;
    float4 f0 = *(const float4*)(x + i);
    float4 f1 = *(const float4*)(x + i + 4);
    u16x8 o;
    o[0]=f2bf(f0.x); o[1]=f2bf(f0.y); o[2]=f2bf(f0.z); o[3]=f2bf(f0.w);
    o[4]=f2bf(f1.x); o[5]=f2bf(f1.y); o[6]=f2bf(f1.z); o[7]=f2bf(f1.w);
    *(u16x8*)(xb + i) = o;
    return;
  }
  const int wi = blockIdx.x - 4096;
  const int z = wi >> 8, r8 = wi & 255;
  const int k0 = (r8 >> 4) * 64, n0 = (r8 & 15) * 64;
  const float* w = (z == 0) ? Wq : (z == 1) ? Wk : (z == 2) ? Wv : Wo;
  const float scale = (z == 0) ? QSCALE : 1.0f;
  u16* wt = wt_all + (size_t)z * Dn * Dn;
  #pragma unroll
  for (int i = 0; i < 4; i++){
    int idx = i*256 + t;
    int r = idx >> 4, c4 = (idx & 15) * 4;
    float4 f = *(const float4*)(w + (size_t)(k0 + r)*Dn + n0 + c4);
    tile[r*66 + c4 + 0] = f2bf(f.x * scale);
    tile[r*66 + c4 + 1] = f2bf(f.y * scale);
    tile[r*66 + c4 + 2] = f2bf(f.z * scale);
    tile[r*66 + c4 + 3] = f2bf(f.w * scale);
  }
  __syncthreads();
  #pragma unroll
  for (int i = 0; i < 4; i++){
    int idx = i*256 + t;
    int nr = idx >> 4, kc4 = (idx & 15) * 4;
    u16x4 o;
    o[0] = tile[(kc4+0)*66 + nr];
    o[1] = tile[(kc4+1)*66 + nr];
    o[2] = tile[(kc4+2)*66 + nr];
    o[3] = tile[(kc4+3)*66 + nr];
    *(u16x4*)(wt + (size_t)(n0 + nr)*Dn + k0 + kc4) = o;
  }
}

// ---------------- QKV GEMM: 128^2 tile, BK=64, A-tri/B-dbuf, 1 barrier/K-tile ----------------
__launch_bounds__(256)
__global__ void gemm_qkv_kernel(const u16* __restrict__ xb, const u16* __restrict__ wt_all,
                                u16* __restrict__ qb, u16* __restrict__ kb, u16* __restrict__ vtb){
  __shared__ u16 sm[40960];   // 80 KB
  const int t = threadIdx.x;
  const int lane = t & 63, wave = t >> 6;
  const int ln = lane & 15, quad = lane >> 4;
  const int wm = wave >> 1, wn = wave & 1;

  // T1: XCD-chunked bijective swizzle (1536 = 8*192), m-outer n-inner within chunk
  const int lin = blockIdx.x;
  const int wg = (lin & 7) * 192 + (lin >> 3);
  const int zsel = wg >> 9;
  const int rem = wg & 511;
  const int m0 = (rem >> 3) * 128;
  const int n0 = (rem & 7) * 128;
  const u16* wt = wt_all + (size_t)zsel * Dn * Dn;

  const u16* ap[4]; const u16* bp[4]; int ldo[4];
  #pragma unroll
  for (int p = 0; p < 4; p++){
    int idx = p*256 + t;
    int r = idx >> 3, g = (idx & 7) ^ (r & 7);
    ap[p] = xb + (size_t)(m0 + r)*Dn + g*8;
    bp[p] = wt + (size_t)(n0 + r)*Dn + g*8;
    ldo[p] = idx * 8;
  }
#define STGA(buf, tt) do { _Pragma("unroll") for (int p = 0; p < 4; p++) \
    G2L16(&sm[(buf) + ldo[p]], ap[p] + (size_t)(tt)*64); } while(0)
#define STGB(buf, tt) do { _Pragma("unroll") for (int p = 0; p < 4; p++) \
    G2L16(&sm[(buf) + ldo[p]], bp[p] + (size_t)(tt)*64); } while(0)

  const int agr0 = ((    quad) ^ (ln & 7)) * 8;
  const int agr1 = ((4 + quad) ^ (ln & 7)) * 8;
  int arow[4], brow[4];
  #pragma unroll
  for (int i = 0; i < 4; i++) arow[i] = (wm*64 + i*16 + ln) * 64;
  #pragma unroll
  for (int j = 0; j < 4; j++) brow[j] = (wn*64 + j*16 + ln) * 64;

  f32x4 acc[4][4] = {};

  STGA(0, 0); STGB(24576, 0); STGA(8192, 1);

  #pragma unroll
  for (int tt = 0; tt < 16; ++tt){
    const int a_cur = (tt % 3) * 8192;
    const int a_pf  = ((tt + 2) % 3) * 8192;
    const int b_cur = 24576 + (tt & 1) * 8192;
    const int b_pf  = 24576 + ((tt + 1) & 1) * 8192;

    if (tt < 15) { VM4(); } else { VM0(); }
    BARRAW(); SCHEDB();

    bf16x8 a01[2][2], bq[4][2];
    #pragma unroll
    for (int i = 0; i < 2; i++){
      a01[i][0] = *(const bf16x8*)&sm[a_cur + arow[i] + agr0];
      a01[i][1] = *(const bf16x8*)&sm[a_cur + arow[i] + agr1];
    }
    #pragma unroll
    for (int j = 0; j < 4; j++){
      bq[j][0] = *(const bf16x8*)&sm[b_cur + brow[j] + agr0];
      bq[j][1] = *(const bf16x8*)&sm[b_cur + brow[j] + agr1];
    }
    SCHEDB();
    if (tt < 15) STGB(b_pf, tt + 1);
    SCHEDB();
    WAIT_LGKM0(); SCHEDB();
    __builtin_amdgcn_s_setprio(1);
    #pragma unroll
    for (int i = 0; i < 2; i++)
      #pragma unroll
      for (int j = 0; j < 4; j++){
        MFMA_B16(acc[i][j], a01[i][0], bq[j][0]);
        MFMA_B16(acc[i][j], a01[i][1], bq[j][1]);
      }
    __builtin_amdgcn_s_setprio(0);

    bf16x8 a23[2][2];
    #pragma unroll
    for (int i = 0; i < 2; i++){
      a23[i][0] = *(const bf16x8*)&sm[a_cur + arow[2+i] + agr0];
      a23[i][1] = *(const bf16x8*)&sm[a_cur + arow[2+i] + agr1];
    }
    SCHEDB();
    if (tt < 14) STGA(a_pf, tt + 2);
    SCHEDB();
    WAIT_LGKM0(); SCHEDB();
    __builtin_amdgcn_s_setprio(1);
    #pragma unroll
    for (int i = 0; i < 2; i++)
      #pragma unroll
      for (int j = 0; j < 4; j++){
        MFMA_B16(acc[2+i][j], a23[i][0], bq[j][0]);
        MFMA_B16(acc[2+i][j], a23[i][1], bq[j][1]);
      }
    __builtin_amdgcn_s_setprio(0);
  }

  __syncthreads();
  u16* Cs = sm;
  if (zsel < 2){
    u16* outp = (zsel == 0) ? qb : kb;
    #pragma unroll
    for (int rb = 0; rb < 4; rb++)
      #pragma unroll
      for (int cb = 0; cb < 4; cb++)
        #pragma unroll
        for (int reg = 0; reg < 4; reg++)
          Cs[(wm*64 + rb*16 + quad*4 + reg)*136 + wn*64 + cb*16 + ln] = f2bf(acc[rb][cb][reg]);
    __syncthreads();
    #pragma unroll
    for (int i = 0; i < 8; i++){
      int idx = i*256 + t;
      int r = idx >> 4, c8 = (idx & 15) * 8;
      bf16x8 vdat = *(const bf16x8*)&Cs[r*136 + c8];
      int row = m0 + r, bb = row >> 11, s = row & 2047;
      int col = n0 + c8, hh = col >> 6, d = col & 63;
      *(bf16x8*)(outp + (((size_t)bb*Hn + hh)*Sn + s)*DHn + d) = vdat;
    }
  } else {
    #pragma unroll
    for (int rb = 0; rb < 4; rb++)
      #pragma unroll
      for (int cb = 0; cb < 4; cb++){
        u16x4 o;
        #pragma unroll
        for (int reg = 0; reg < 4; reg++) o[reg] = f2bf(acc[rb][cb][reg]);
        *(u16x4*)&Cs[(wn*64 + cb*16 + ln)*136 + wm*64 + rb*16 + quad*4] = o;
      }
    __syncthreads();
    #pragma unroll
    for (int i = 0; i < 8; i++){
      int idx = i*256 + t;
      int c = idx >> 4, r8 = (idx & 15) * 8;
      bf16x8 vdat = *(const bf16x8*)&Cs[c*136 + r8];
      int col = n0 + c, hh = col >> 6, d = col & 63;
      int row = m0 + r8, bb = row >> 11, s = row & 2047;
      *(bf16x8*)(vtb + (((size_t)bb*Hn + hh)*DHn + d)*Sn + s) = vdat;
    }
  }
#undef STGA
#undef STGB
}

// ---------------- attention: 8 waves x 32 q, r3 cadence, K via global_load_lds, x2 unroll ----------------
// Structure == r3 (2-deep K/V LDS, one compute + one prefetch per barrier segment,
// VM0 covers exactly the 2 vm-ops issued before compute). Deltas vs r3:
//  - K staged by global_load_lds with pre-swizzled per-lane SOURCE (linear LDS dest):
//    frees rk (8 VGPR), kills K ds_write + its addressing.
//  - kt loop unrolled x2 with LITERAL slot indices: all ds addresses become
//    base+immediate (no per-tile cur/nxt select VALU).
// Numeric op order identical to r3.
__launch_bounds__(512, 4)
__global__ void attn_kernel(const u16* q, const u16* __restrict__ k,
                            const u16* __restrict__ vt, u16* z){
  __shared__ u16 Ks[2][64*64];   // [key][d], swizzled granules
  __shared__ u16 Vs[2][64*64];   // [d][key'] column-shuffled + swizzled
  const int t = threadIdx.x;
  const int wave = t >> 6, lane = t & 63;
  const int ln = lane & 15, quad = lane >> 4;
  const int lin = blockIdx.x + 8*(blockIdx.y + 16*blockIdx.z);
  const int wgs = (lin & 7)*64 + (lin >> 3);
  const int qt = wgs & 7, h = (wgs >> 3) & 15, b = wgs >> 7;
  const size_t bh = (size_t)b * Hn + h;
  const int q0 = qt*256 + wave*32;
  const u16* qp = q + bh * Sn * DHn;
  const u16* kp = k + bh * Sn * DHn;
  const u16* vp = vt + bh * DHn * Sn;

  bf16x8 qf[2][2];
  #pragma unroll
  for (int n = 0; n < 2; n++)
    #pragma unroll
    for (int kq = 0; kq < 2; kq++)
      qf[n][kq] = *(const bf16x8*)(qp + (size_t)(q0 + n*16 + ln)*DHn + kq*32 + quad*8);

  f32x4 zacc[4][2] = {};
  float dacc[2] = {0.f, 0.f};

  // staging coords: thread t handles granule a of row r (512 thr = 64x8 granules)
  const int r = t >> 3, a = t & 7;
  const u16* kgp = kp + (size_t)r*DHn + ((a ^ (r & 7)) * 8);
  const int kldo = t * 8;
#define STGK(slot, tt) G2L16(&Ks[slot][kldo], kgp + (size_t)(tt)*4096)
  const int ksg = a >> 2, q1 = ((a&3)*2)&3, h1 = (a&3) >> 1;
  const int vc1 = ksg*32 + q1*8 + h1*4;
  const int vc2 = ksg*32 + (((q1+1)&3))*8 + h1*4;
  const int vpos1 = r*64 + ((vc1>>3) ^ (r&7))*8 + (vc1 & 7);
  const int vpos2 = r*64 + ((vc2>>3) ^ (r&7))*8 + (vc2 & 7);
  const u16* vgp = vp + (size_t)r*Sn + a*8;
#define WRV(slot, rv) do { \
    u16x4 lo_ = *(u16x4*)&(rv); \
    u16x4 hi_ = *((u16x4*)&(rv) + 1); \
    *(u16x4*)&Vs[slot][vpos1] = lo_; \
    *(u16x4*)&Vs[slot][vpos2] = hi_; } while(0)

  // swizzled read column offsets
  const int kg0 = ((    quad) ^ (ln & 7)) * 8;
  const int kg1 = ((4 + quad) ^ (ln & 7)) * 8;

#define TILE_COMPUTE(slot) do { \
    const u16* Kc = Ks[slot]; \
    const u16* Vc = Vs[slot]; \
    _Pragma("unroll") \
    for (int ks = 0; ks < 2; ks++){ \
      f32x4 sacc[2][2] = {}; \
      _Pragma("unroll") \
      for (int kq = 0; kq < 2; kq++){ \
        const int kgo = kq ? kg1 : kg0; \
        bf16x8 ka[2]; \
        _Pragma("unroll") \
        for (int m2 = 0; m2 < 2; m2++) \
          ka[m2] = *(const bf16x8*)&Kc[((2*ks + m2)*16 + ln)*64 + kgo]; \
        __builtin_amdgcn_s_setprio(1); \
        _Pragma("unroll") \
        for (int m2 = 0; m2 < 2; m2++) \
          _Pragma("unroll") \
          for (int n = 0; n < 2; n++) \
            sacc[m2][n] = __builtin_amdgcn_mfma_f32_16x16x32_bf16(ka[m2], qf[n][kq], sacc[m2][n], 0, 0, 0); \
        __builtin_amdgcn_s_setprio(0); \
      } \
      B8 pb[2]; \
      _Pragma("unroll") \
      for (int n = 0; n < 2; n++){ \
        f32x4 s0 = sacc[0][n], s1 = sacc[1][n]; \
        float a0 = EXP2(s0[0]), a1 = EXP2(s0[1]), a2 = EXP2(s0[2]), a3 = EXP2(s0[3]); \
        float b0 = EXP2(s1[0]), b1 = EXP2(s1[1]), b2 = EXP2(s1[2]), b3 = EXP2(s1[3]); \
        dacc[n] += ((a0 + a1) + (a2 + a3)) + ((b0 + b1) + (b2 + b3)); \
        pb[n].u = (u32x4){pack_bf2(a0, a1), pack_bf2(a2, a3), pack_bf2(b0, b1), pack_bf2(b2, b3)}; \
      } \
      const int vgo = ks ? kg1 : kg0; \
      _Pragma("unroll") \
      for (int mtd = 0; mtd < 4; mtd++){ \
        bf16x8 va = *(const bf16x8*)&Vc[(mtd*16 + ln)*64 + vgo]; \
        __builtin_amdgcn_s_setprio(1); \
        _Pragma("unroll") \
        for (int n = 0; n < 2; n++) \
          zacc[mtd][n] = __builtin_amdgcn_mfma_f32_16x16x32_bf16(va, pb[n].s, zacc[mtd][n], 0, 0, 0); \
        __builtin_amdgcn_s_setprio(0); \
      } \
    } \
  } while(0)

  bf16x8 rv;

  // prologue: tile 0 -> slot 0
  STGK(0, 0);
  rv = *(const bf16x8*)(vgp);
  VM0();
  WRV(0, rv);
  WAIT_LGKM0();
  BARRAW();

  for (int kt2 = 0; kt2 < 16; ++kt2){
    // ---- tile T = 2*kt2 in slot 0; prefetch T+1 -> slot 1 (always valid: T+1 <= 31)
    {
      const int T = 2*kt2;
      STGK(1, T+1);
      rv = *(const bf16x8*)(vgp + (size_t)(T+1)*64);
      SCHEDB();
      TILE_COMPUTE(0);
      VM0();
      WRV(1, rv);
      WAIT_LGKM0();
      BARRAW();
    }
    // ---- tile T = 2*kt2+1 in slot 1; prefetch T+1 -> slot 0 (skip on last)
    {
      const int T = 2*kt2 + 1;
      if (T + 1 < 32){
        STGK(0, T+1);
        rv = *(const bf16x8*)(vgp + (size_t)(T+1)*64);
        SCHEDB();
      }
      TILE_COMPUTE(1);
      if (T + 1 < 32){
        VM0();
        WRV(0, rv);
        WAIT_LGKM0();
        BARRAW();
      }
    }
  }
#undef STGK
#undef WRV
#undef TILE_COMPUTE

  float inv[2];
  #pragma unroll
  for (int n = 0; n < 2; n++){
    float d = dacc[n];
    d += __shfl_xor(d, 16, 64);
    d += __shfl_xor(d, 32, 64);
    inv[n] = 1.0f / d;
  }

  #pragma unroll
  for (int mtd = 0; mtd < 4; mtd++)
    #pragma unroll
    for (int n = 0; n < 2; n++){
      u16x4 o;
      #pragma unroll
      for (int j = 0; j < 4; j++) o[j] = f2bf(zacc[mtd][n][j] * inv[n]);
      *(u16x4*)(z + (bh*Sn + (size_t)(q0 + n*16 + ln))*DHn + mtd*16 + quad*4) = o;
    }
}

// ---------------- out = z * Wout^T + x: same A-tri/B-dbuf template, K-chunk 64 == head ----------------
__launch_bounds__(256)
__global__ void gemm_out_kernel(const u16* __restrict__ zb, const u16* __restrict__ wt,
                                const float* __restrict__ x, float* __restrict__ out){
  __shared__ u16 sm[40960];   // 80 KB
  const int t = threadIdx.x;
  const int lane = t & 63, wave = t >> 6;
  const int ln = lane & 15, quad = lane >> 4;
  const int wm = wave >> 1, wn = wave & 1;

  const int lin = blockIdx.x;
  const int wg = (lin & 7) * 64 + (lin >> 3);
  const int m0 = (wg >> 3) * 128;
  const int n0 = (wg & 7) * 128;

  const u16* ap[4]; const u16* bp[4]; int ldo[4];
  #pragma unroll
  for (int p = 0; p < 4; p++){
    int idx = p*256 + t;
    int r = idx >> 3, g = (idx & 7) ^ (r & 7);
    int row = m0 + r, bb = row >> 11, s = row & 2047;
    ap[p] = zb + ((size_t)bb*Hn*Sn + s)*DHn + g*8;    // head-0 base; head stride Sn*DHn
    bp[p] = wt + (size_t)(n0 + r)*Dn + g*8;
    ldo[p] = idx * 8;
  }
#define STGA(buf, tt) do { _Pragma("unroll") for (int p = 0; p < 4; p++) \
    G2L16(&sm[(buf) + ldo[p]], ap[p] + (size_t)(tt)*Sn*DHn); } while(0)
#define STGB(buf, tt) do { _Pragma("unroll") for (int p = 0; p < 4; p++) \
    G2L16(&sm[(buf) + ldo[p]], bp[p] + (size_t)(tt)*64); } while(0)

  const int agr0 = ((    quad) ^ (ln & 7)) * 8;
  const int agr1 = ((4 + quad) ^ (ln & 7)) * 8;
  int arow[4], brow[4];
  #pragma unroll
  for (int i = 0; i < 4; i++) arow[i] = (wm*64 + i*16 + ln) * 64;
  #pragma unroll
  for (int j = 0; j < 4; j++) brow[j] = (wn*64 + j*16 + ln) * 64;

  f32x4 acc[4][4] = {};
  STGA(0, 0); STGB(24576, 0); STGA(8192, 1);

  #pragma unroll
  for (int tt = 0; tt < 16; ++tt){
    const int a_cur = (tt % 3) * 8192;
    const int a_pf  = ((tt + 2) % 3) * 8192;
    const int b_cur = 24576 + (tt & 1) * 8192;
    const int b_pf  = 24576 + ((tt + 1) & 1) * 8192;

    if (tt < 15) { VM4(); } else { VM0(); }
    BARRAW(); SCHEDB();

    bf16x8 a01[2][2], bq[4][2];
    #pragma unroll
    for (int i = 0; i < 2; i++){
      a01[i][0] = *(const bf16x8*)&sm[a_cur + arow[i] + agr0];
      a01[i][1] = *(const bf16x8*)&sm[a_cur + arow[i] + agr1];
    }
    #pragma unroll
    for (int j = 0; j < 4; j++){
      bq[j][0] = *(const bf16x8*)&sm[b_cur + brow[j] + agr0];
      bq[j][1] = *(const bf16x8*)&sm[b_cur + brow[j] + agr1];
    }
    SCHEDB();
    if (tt < 15) STGB(b_pf, tt + 1);
    SCHEDB();
    WAIT_LGKM0(); SCHEDB();
    __builtin_amdgcn_s_setprio(1);
    #pragma unroll
    for (int i = 0; i < 2; i++)
      #pragma unroll
      for (int j = 0; j < 4; j++){
        MFMA_B16(acc[i][j], a01[i][0], bq[j][0]);
        MFMA_B16(acc[i][j], a01[i][1], bq[j][1]);
      }
    __builtin_amdgcn_s_setprio(0);

    bf16x8 a23[2][2];
    #pragma unroll
    for (int i = 0; i < 2; i++){
      a23[i][0] = *(const bf16x8*)&sm[a_cur + arow[2+i] + agr0];
      a23[i][1] = *(const bf16x8*)&sm[a_cur + arow[2+i] + agr1];
    }
    SCHEDB();
    if (tt < 14) STGA(a_pf, tt + 2);
    SCHEDB();
    WAIT_LGKM0(); SCHEDB();
    __builtin_amdgcn_s_setprio(1);
    #pragma unroll
    for (int i = 0; i < 2; i++)
      #pragma unroll
      for (int j = 0; j < 4; j++){
        MFMA_B16(acc[2+i][j], a23[i][0], bq[j][0]);
        MFMA_B16(acc[2+i][j], a23[i][1], bq[j][1]);
      }
    __builtin_amdgcn_s_setprio(0);
  }

  #pragma unroll
  for (int rb = 0; rb < 4; rb++)
    #pragma unroll
    for (int cb = 0; cb < 4; cb++)
      #pragma unroll
      for (int reg = 0; reg < 4; reg++){
        int row = m0 + wm*64 + rb*16 + quad*4 + reg;
        int col = n0 + wn*64 + cb*16 + ln;
        size_t off = (size_t)row*Dn + col;
        out[off] = acc[rb][cb][reg] + x[off];
      }
#undef STGA
#undef STGB
}

extern "C" void kernel_launch(void* const* d_in, const int* in_sizes, int n_in,
                              void* d_out, int out_size, void* d_ws, size_t ws_size,
                              hipStream_t stream){
  const float* x    = (const float*)d_in[0];
  const float* Wq   = (const float*)d_in[2];
  const float* Wk   = (const float*)d_in[3];
  const float* Wv   = (const float*)d_in[4];
  const float* Wout = (const float*)d_in[5];
  float* out = (float*)d_out;

  u16* ws = (u16*)d_ws;
  const size_t NW = (size_t)Dn * Dn;
  const size_t NX = (size_t)Bn * Sn * Dn;
  u16* wt  = ws;                // Wq^T(scaled),Wk^T,Wv^T,Wout^T
  u16* xb  = wt + 4*NW;         // x bf16
  u16* qb  = xb + NX;           // Q [b,h,s,d] (attn writes z in-place)
  u16* kb  = qb + NX;           // K [b,h,s,d]
  u16* vtb = kb + NX;           // Vt [b,h,d,s] (written directly by gemm_qkv)

  prep_kernel     <<<dim3(4096 + 1024), dim3(256), 0, stream>>>(x, Wq, Wk, Wv, Wout, xb, wt);
  gemm_qkv_kernel <<<dim3(1536), dim3(256), 0, stream>>>(xb, wt, qb, kb, vtb);
  attn_kernel     <<<dim3(8,16,4), dim3(512), 0, stream>>>(qb, kb, vtb, qb);
  gemm_out_kernel <<<dim3(512), dim3(256), 0, stream>>>(qb, wt + 3*NW, x, out);
}

// Round 7
// 263.777 us; speedup vs baseline: 2.1535x; 1.1046x over previous
//
#include <hip/hip_runtime.h>

#define Bn 4
#define Sn 2048
#define Dn 1024
#define Hn 16
#define DHn 64

typedef float f32x4 __attribute__((ext_vector_type(4)));
typedef short bf16x8 __attribute__((ext_vector_type(8)));
typedef unsigned short u16;
typedef unsigned int u32;
typedef unsigned short u16x8 __attribute__((ext_vector_type(8)));
typedef unsigned short u16x4 __attribute__((ext_vector_type(4)));
typedef u32 u32x4 __attribute__((ext_vector_type(4)));

union B8 { u32x4 u; bf16x8 s; u16x8 h; };

__device__ __forceinline__ u16 f2bf(float f){
  union { float f; u32 u; } v; v.f = f;
  return (u16)((v.u + 0x7fffu + ((v.u >> 16) & 1u)) >> 16);
}

// truncating pack: two fp32 -> {bf16(lo) | bf16(hi)<<16}. P>0 -> -0.2% uniform bias, negligible.
__device__ __forceinline__ u32 pack_bf2(float lo, float hi){
  union { float f; u32 u; } a, b;
  a.f = lo; b.f = hi;
  return __builtin_amdgcn_perm(b.u, a.u, 0x07060302u);
}

#if __has_builtin(__builtin_amdgcn_exp2f)
#define EXP2(x) __builtin_amdgcn_exp2f(x)
#define QSCALE 0.18033688011112042f   /* 0.125 * log2(e) */
#else
#define EXP2(x) __expf(x)
#define QSCALE 0.125f
#endif

#if __has_builtin(__builtin_amdgcn_global_load_lds)
#define G2L16(l, g) __builtin_amdgcn_global_load_lds((const __attribute__((address_space(1))) u32*)(g), \
                                                     (__attribute__((address_space(3))) u32*)(l), 16, 0, 0)
#else
#define G2L16(l, g) (*(bf16x8*)(l) = *(const bf16x8*)(g))
#endif

#define MFMA_B16(d, va, vb) (d) = __builtin_amdgcn_mfma_f32_16x16x32_bf16((va), (vb), (d), 0, 0, 0)
#define BARRAW() __builtin_amdgcn_s_barrier()
#define WAIT_LGKM0() asm volatile("s_waitcnt lgkmcnt(0)" ::: "memory")
#define VM4() asm volatile("s_waitcnt vmcnt(4)" ::: "memory")
#define VM0() asm volatile("s_waitcnt vmcnt(0)" ::: "memory")
#define SCHEDB() __builtin_amdgcn_sched_barrier(0)

// ---------------- merged prep: cast x (blocks 0..4095) + 4 weights (4096..5119) ----------------
__global__ void prep_kernel(const float* __restrict__ x,
                            const float* __restrict__ Wq, const float* __restrict__ Wk,
                            const float* __restrict__ Wv, const float* __restrict__ Wo,
                            u16* __restrict__ xb, u16* __restrict__ wt_all){
  __shared__ u16 tile[64*66];
  const int t = threadIdx.x;
  if (blockIdx.x < 4096){
    size_t i = ((size_t)blockIdx.x * 256 + t) * 8;
    float4 f0 = *(const float4*)(x + i);
    float4 f1 = *(const float4*)(x + i + 4);
    u16x8 o;
    o[0]=f2bf(f0.x); o[1]=f2bf(f0.y); o[2]=f2bf(f0.z); o[3]=f2bf(f0.w);
    o[4]=f2bf(f1.x); o[5]=f2bf(f1.y); o[6]=f2bf(f1.z); o[7]=f2bf(f1.w);
    *(u16x8*)(xb + i) = o;
    return;
  }
  const int wi = blockIdx.x - 4096;
  const int z = wi >> 8, r8 = wi & 255;
  const int k0 = (r8 >> 4) * 64, n0 = (r8 & 15) * 64;
  const float* w = (z == 0) ? Wq : (z == 1) ? Wk : (z == 2) ? Wv : Wo;
  const float scale = (z == 0) ? QSCALE : 1.0f;
  u16* wt = wt_all + (size_t)z * Dn * Dn;
  #pragma unroll
  for (int i = 0; i < 4; i++){
    int idx = i*256 + t;
    int r = idx >> 4, c4 = (idx & 15) * 4;
    float4 f = *(const float4*)(w + (size_t)(k0 + r)*Dn + n0 + c4);
    tile[r*66 + c4 + 0] = f2bf(f.x * scale);
    tile[r*66 + c4 + 1] = f2bf(f.y * scale);
    tile[r*66 + c4 + 2] = f2bf(f.z * scale);
    tile[r*66 + c4 + 3] = f2bf(f.w * scale);
  }
  __syncthreads();
  #pragma unroll
  for (int i = 0; i < 4; i++){
    int idx = i*256 + t;
    int nr = idx >> 4, kc4 = (idx & 15) * 4;
    u16x4 o;
    o[0] = tile[(kc4+0)*66 + nr];
    o[1] = tile[(kc4+1)*66 + nr];
    o[2] = tile[(kc4+2)*66 + nr];
    o[3] = tile[(kc4+3)*66 + nr];
    *(u16x4*)(wt + (size_t)(n0 + nr)*Dn + k0 + kc4) = o;
  }
}

// ---------------- QKV GEMM: 128^2 tile, BK=64, A-tri/B-dbuf, 1 barrier/K-tile ----------------
__launch_bounds__(256)
__global__ void gemm_qkv_kernel(const u16* __restrict__ xb, const u16* __restrict__ wt_all,
                                u16* __restrict__ qb, u16* __restrict__ kb, u16* __restrict__ vtb){
  __shared__ u16 sm[40960];   // 80 KB
  const int t = threadIdx.x;
  const int lane = t & 63, wave = t >> 6;
  const int ln = lane & 15, quad = lane >> 4;
  const int wm = wave >> 1, wn = wave & 1;

  // T1: XCD-chunked bijective swizzle (1536 = 8*192), m-outer n-inner within chunk
  const int lin = blockIdx.x;
  const int wg = (lin & 7) * 192 + (lin >> 3);
  const int zsel = wg >> 9;
  const int rem = wg & 511;
  const int m0 = (rem >> 3) * 128;
  const int n0 = (rem & 7) * 128;
  const u16* wt = wt_all + (size_t)zsel * Dn * Dn;

  const u16* ap[4]; const u16* bp[4]; int ldo[4];
  #pragma unroll
  for (int p = 0; p < 4; p++){
    int idx = p*256 + t;
    int r = idx >> 3, g = (idx & 7) ^ (r & 7);
    ap[p] = xb + (size_t)(m0 + r)*Dn + g*8;
    bp[p] = wt + (size_t)(n0 + r)*Dn + g*8;
    ldo[p] = idx * 8;
  }
#define STGA(buf, tt) do { _Pragma("unroll") for (int p = 0; p < 4; p++) \
    G2L16(&sm[(buf) + ldo[p]], ap[p] + (size_t)(tt)*64); } while(0)
#define STGB(buf, tt) do { _Pragma("unroll") for (int p = 0; p < 4; p++) \
    G2L16(&sm[(buf) + ldo[p]], bp[p] + (size_t)(tt)*64); } while(0)

  const int agr0 = ((    quad) ^ (ln & 7)) * 8;
  const int agr1 = ((4 + quad) ^ (ln & 7)) * 8;
  int arow[4], brow[4];
  #pragma unroll
  for (int i = 0; i < 4; i++) arow[i] = (wm*64 + i*16 + ln) * 64;
  #pragma unroll
  for (int j = 0; j < 4; j++) brow[j] = (wn*64 + j*16 + ln) * 64;

  f32x4 acc[4][4] = {};

  STGA(0, 0); STGB(24576, 0); STGA(8192, 1);

  #pragma unroll
  for (int tt = 0; tt < 16; ++tt){
    const int a_cur = (tt % 3) * 8192;
    const int a_pf  = ((tt + 2) % 3) * 8192;
    const int b_cur = 24576 + (tt & 1) * 8192;
    const int b_pf  = 24576 + ((tt + 1) & 1) * 8192;

    if (tt < 15) { VM4(); } else { VM0(); }
    BARRAW(); SCHEDB();

    bf16x8 a01[2][2], bq[4][2];
    #pragma unroll
    for (int i = 0; i < 2; i++){
      a01[i][0] = *(const bf16x8*)&sm[a_cur + arow[i] + agr0];
      a01[i][1] = *(const bf16x8*)&sm[a_cur + arow[i] + agr1];
    }
    #pragma unroll
    for (int j = 0; j < 4; j++){
      bq[j][0] = *(const bf16x8*)&sm[b_cur + brow[j] + agr0];
      bq[j][1] = *(const bf16x8*)&sm[b_cur + brow[j] + agr1];
    }
    SCHEDB();
    if (tt < 15) STGB(b_pf, tt + 1);
    SCHEDB();
    WAIT_LGKM0(); SCHEDB();
    __builtin_amdgcn_s_setprio(1);
    #pragma unroll
    for (int i = 0; i < 2; i++)
      #pragma unroll
      for (int j = 0; j < 4; j++){
        MFMA_B16(acc[i][j], a01[i][0], bq[j][0]);
        MFMA_B16(acc[i][j], a01[i][1], bq[j][1]);
      }
    __builtin_amdgcn_s_setprio(0);

    bf16x8 a23[2][2];
    #pragma unroll
    for (int i = 0; i < 2; i++){
      a23[i][0] = *(const bf16x8*)&sm[a_cur + arow[2+i] + agr0];
      a23[i][1] = *(const bf16x8*)&sm[a_cur + arow[2+i] + agr1];
    }
    SCHEDB();
    if (tt < 14) STGA(a_pf, tt + 2);
    SCHEDB();
    WAIT_LGKM0(); SCHEDB();
    __builtin_amdgcn_s_setprio(1);
    #pragma unroll
    for (int i = 0; i < 2; i++)
      #pragma unroll
      for (int j = 0; j < 4; j++){
        MFMA_B16(acc[2+i][j], a23[i][0], bq[j][0]);
        MFMA_B16(acc[2+i][j], a23[i][1], bq[j][1]);
      }
    __builtin_amdgcn_s_setprio(0);
  }

  __syncthreads();
  u16* Cs = sm;
  if (zsel < 2){
    u16* outp = (zsel == 0) ? qb : kb;
    #pragma unroll
    for (int rb = 0; rb < 4; rb++)
      #pragma unroll
      for (int cb = 0; cb < 4; cb++)
        #pragma unroll
        for (int reg = 0; reg < 4; reg++)
          Cs[(wm*64 + rb*16 + quad*4 + reg)*136 + wn*64 + cb*16 + ln] = f2bf(acc[rb][cb][reg]);
    __syncthreads();
    #pragma unroll
    for (int i = 0; i < 8; i++){
      int idx = i*256 + t;
      int r = idx >> 4, c8 = (idx & 15) * 8;
      bf16x8 vdat = *(const bf16x8*)&Cs[r*136 + c8];
      int row = m0 + r, bb = row >> 11, s = row & 2047;
      int col = n0 + c8, hh = col >> 6, d = col & 63;
      *(bf16x8*)(outp + (((size_t)bb*Hn + hh)*Sn + s)*DHn + d) = vdat;
    }
  } else {
    #pragma unroll
    for (int rb = 0; rb < 4; rb++)
      #pragma unroll
      for (int cb = 0; cb < 4; cb++){
        u16x4 o;
        #pragma unroll
        for (int reg = 0; reg < 4; reg++) o[reg] = f2bf(acc[rb][cb][reg]);
        *(u16x4*)&Cs[(wn*64 + cb*16 + ln)*136 + wm*64 + rb*16 + quad*4] = o;
      }
    __syncthreads();
    #pragma unroll
    for (int i = 0; i < 8; i++){
      int idx = i*256 + t;
      int c = idx >> 4, r8 = (idx & 15) * 8;
      bf16x8 vdat = *(const bf16x8*)&Cs[c*136 + r8];
      int col = n0 + c, hh = col >> 6, d = col & 63;
      int row = m0 + r8, bb = row >> 11, s = row & 2047;
      *(bf16x8*)(vtb + (((size_t)bb*Hn + hh)*DHn + d)*Sn + s) = vdat;
    }
  }
#undef STGA
#undef STGB
}

// ---------------- attention: 8 waves x 32 q, pair-phase pipeline, relaxed VGPR budget ----------------
// r5 structure (1 barrier / 2 tiles, 4-deep K/V slots) + r6's K-via-global_load_lds
// (both HW-validated for correctness), now under __launch_bounds__(512, 2):
// VGPR cap >=256 so the body cannot spill (r4/r5/r6 all spilled at the (512,4)
// 64-VGPR cap - that confound, not the structure, caused the regressions).
// Occupancy floor 8 waves/CU == r2's level, which r2/r3 proved is NOT the
// binding resource. VM0 drains 4 vm-ops issued a full 2-tile compute window
// earlier (~1400 cyc) -> HBM/L3 latency fully covered. Numeric op order is
// bit-identical to r3.
__launch_bounds__(512, 2)
__global__ void attn_kernel(const u16* q, const u16* __restrict__ k,
                            const u16* __restrict__ vt, u16* z){
  __shared__ u16 Ks[4][64*64];   // [key][d], swizzled granules (K-DMA linear dest)
  __shared__ u16 Vs[4][64*64];   // [d][key'] column-shuffled + swizzled
  const int t = threadIdx.x;
  const int wave = t >> 6, lane = t & 63;
  const int ln = lane & 15, quad = lane >> 4;
  const int lin = blockIdx.x + 8*(blockIdx.y + 16*blockIdx.z);
  const int wgs = (lin & 7)*64 + (lin >> 3);
  const int qt = wgs & 7, h = (wgs >> 3) & 15, b = wgs >> 7;
  const size_t bh = (size_t)b * Hn + h;
  const int q0 = qt*256 + wave*32;
  const u16* qp = q + bh * Sn * DHn;
  const u16* kp = k + bh * Sn * DHn;
  const u16* vp = vt + bh * DHn * Sn;

  bf16x8 qf[2][2];
  #pragma unroll
  for (int n = 0; n < 2; n++)
    #pragma unroll
    for (int kq = 0; kq < 2; kq++)
      qf[n][kq] = *(const bf16x8*)(qp + (size_t)(q0 + n*16 + ln)*DHn + kq*32 + quad*8);

  f32x4 zacc[4][2] = {};
  float dacc[2] = {0.f, 0.f};

  // staging coords: thread t handles granule a of row r (512 thr = 64x8 granules)
  const int r = t >> 3, a = t & 7;
  // K: DMA with pre-swizzled global source, linear LDS dest (r6-validated)
  const u16* kgp = kp + (size_t)r*DHn + ((a ^ (r & 7)) * 8);
  const int kldo = t * 8;
#define STGK(slot, tt) G2L16(&Ks[slot][kldo], kgp + (size_t)(tt)*4096)
  // V: register-staged, column-shuffled + swizzled write (r3-validated)
  const int ksg = a >> 2, q1 = ((a&3)*2)&3, h1 = (a&3) >> 1;
  const int vc1 = ksg*32 + q1*8 + h1*4;
  const int vc2 = ksg*32 + (((q1+1)&3))*8 + h1*4;
  const int vpos1 = r*64 + ((vc1>>3) ^ (r&7))*8 + (vc1 & 7);
  const int vpos2 = r*64 + ((vc2>>3) ^ (r&7))*8 + (vc2 & 7);
  const u16* vgp = vp + (size_t)r*Sn + a*8;
#define WRV(slot, rv) do { \
    u16x4 lo_ = *(u16x4*)&(rv); \
    u16x4 hi_ = *((u16x4*)&(rv) + 1); \
    *(u16x4*)&Vs[slot][vpos1] = lo_; \
    *(u16x4*)&Vs[slot][vpos2] = hi_; } while(0)

  // swizzled read column offsets
  const int kg0 = ((    quad) ^ (ln & 7)) * 8;
  const int kg1 = ((4 + quad) ^ (ln & 7)) * 8;

#define TILE_COMPUTE(slot) do { \
    const u16* Kc = Ks[slot]; \
    const u16* Vc = Vs[slot]; \
    _Pragma("unroll") \
    for (int ks = 0; ks < 2; ks++){ \
      f32x4 sacc[2][2] = {}; \
      _Pragma("unroll") \
      for (int kq = 0; kq < 2; kq++){ \
        const int kgo = kq ? kg1 : kg0; \
        bf16x8 ka[2]; \
        _Pragma("unroll") \
        for (int m2 = 0; m2 < 2; m2++) \
          ka[m2] = *(const bf16x8*)&Kc[((2*ks + m2)*16 + ln)*64 + kgo]; \
        __builtin_amdgcn_s_setprio(1); \
        _Pragma("unroll") \
        for (int m2 = 0; m2 < 2; m2++) \
          _Pragma("unroll") \
          for (int n = 0; n < 2; n++) \
            sacc[m2][n] = __builtin_amdgcn_mfma_f32_16x16x32_bf16(ka[m2], qf[n][kq], sacc[m2][n], 0, 0, 0); \
        __builtin_amdgcn_s_setprio(0); \
      } \
      B8 pb[2]; \
      _Pragma("unroll") \
      for (int n = 0; n < 2; n++){ \
        f32x4 s0 = sacc[0][n], s1 = sacc[1][n]; \
        float a0 = EXP2(s0[0]), a1 = EXP2(s0[1]), a2 = EXP2(s0[2]), a3 = EXP2(s0[3]); \
        float b0 = EXP2(s1[0]), b1 = EXP2(s1[1]), b2 = EXP2(s1[2]), b3 = EXP2(s1[3]); \
        dacc[n] += ((a0 + a1) + (a2 + a3)) + ((b0 + b1) + (b2 + b3)); \
        pb[n].u = (u32x4){pack_bf2(a0, a1), pack_bf2(a2, a3), pack_bf2(b0, b1), pack_bf2(b2, b3)}; \
      } \
      const int vgo = ks ? kg1 : kg0; \
      _Pragma("unroll") \
      for (int mtd = 0; mtd < 4; mtd++){ \
        bf16x8 va = *(const bf16x8*)&Vc[(mtd*16 + ln)*64 + vgo]; \
        __builtin_amdgcn_s_setprio(1); \
        _Pragma("unroll") \
        for (int n = 0; n < 2; n++) \
          zacc[mtd][n] = __builtin_amdgcn_mfma_f32_16x16x32_bf16(va, pb[n].s, zacc[mtd][n], 0, 0, 0); \
        __builtin_amdgcn_s_setprio(0); \
      } \
    } \
  } while(0)

  bf16x8 rv0, rv1;

  // prologue: stage tiles 0,1 into slots 0,1
  STGK(0, 0); STGK(1, 1);
  rv0 = *(const bf16x8*)(vgp);
  rv1 = *(const bf16x8*)(vgp + 64);
  VM0();
  WRV(0, rv0); WRV(1, rv1);
  WAIT_LGKM0();
  BARRAW();

  for (int p2 = 0; p2 < 8; ++p2){
    // ---- phase A: compute slots {0,1} (tiles 4p2, 4p2+1); stage tiles +2,+3 -> slots {2,3}
    {
      const int T = 4*p2;
      STGK(2, T+2); STGK(3, T+3);
      rv0 = *(const bf16x8*)(vgp + (size_t)(T+2)*64);
      rv1 = *(const bf16x8*)(vgp + (size_t)(T+3)*64);
      SCHEDB();
      TILE_COMPUTE(0);
      TILE_COMPUTE(1);
      VM0();
      WRV(2, rv0); WRV(3, rv1);
      WAIT_LGKM0();
      BARRAW();
    }
    // ---- phase B: compute slots {2,3} (tiles 4p2+2, 4p2+3); stage tiles +4,+5 -> slots {0,1}
    {
      const int T = 4*p2 + 2;
      if (T + 2 < 32){
        STGK(0, T+2); STGK(1, T+3);
        rv0 = *(const bf16x8*)(vgp + (size_t)(T+2)*64);
        rv1 = *(const bf16x8*)(vgp + (size_t)(T+3)*64);
        SCHEDB();
      }
      TILE_COMPUTE(2);
      TILE_COMPUTE(3);
      if (T + 2 < 32){
        VM0();
        WRV(0, rv0); WRV(1, rv1);
        WAIT_LGKM0();
        BARRAW();
      }
    }
  }
#undef STGK
#undef WRV
#undef TILE_COMPUTE

  float inv[2];
  #pragma unroll
  for (int n = 0; n < 2; n++){
    float d = dacc[n];
    d += __shfl_xor(d, 16, 64);
    d += __shfl_xor(d, 32, 64);
    inv[n] = 1.0f / d;
  }

  #pragma unroll
  for (int mtd = 0; mtd < 4; mtd++)
    #pragma unroll
    for (int n = 0; n < 2; n++){
      u16x4 o;
      #pragma unroll
      for (int j = 0; j < 4; j++) o[j] = f2bf(zacc[mtd][n][j] * inv[n]);
      *(u16x4*)(z + (bh*Sn + (size_t)(q0 + n*16 + ln))*DHn + mtd*16 + quad*4) = o;
    }
}

// ---------------- out = z * Wout^T + x: same A-tri/B-dbuf template, K-chunk 64 == head ----------------
__launch_bounds__(256)
__global__ void gemm_out_kernel(const u16* __restrict__ zb, const u16* __restrict__ wt,
                                const float* __restrict__ x, float* __restrict__ out){
  __shared__ u16 sm[40960];   // 80 KB
  const int t = threadIdx.x;
  const int lane = t & 63, wave = t >> 6;
  const int ln = lane & 15, quad = lane >> 4;
  const int wm = wave >> 1, wn = wave & 1;

  const int lin = blockIdx.x;
  const int wg = (lin & 7) * 64 + (lin >> 3);
  const int m0 = (wg >> 3) * 128;
  const int n0 = (wg & 7) * 128;

  const u16* ap[4]; const u16* bp[4]; int ldo[4];
  #pragma unroll
  for (int p = 0; p < 4; p++){
    int idx = p*256 + t;
    int r = idx >> 3, g = (idx & 7) ^ (r & 7);
    int row = m0 + r, bb = row >> 11, s = row & 2047;
    ap[p] = zb + ((size_t)bb*Hn*Sn + s)*DHn + g*8;    // head-0 base; head stride Sn*DHn
    bp[p] = wt + (size_t)(n0 + r)*Dn + g*8;
    ldo[p] = idx * 8;
  }
#define STGA(buf, tt) do { _Pragma("unroll") for (int p = 0; p < 4; p++) \
    G2L16(&sm[(buf) + ldo[p]], ap[p] + (size_t)(tt)*Sn*DHn); } while(0)
#define STGB(buf, tt) do { _Pragma("unroll") for (int p = 0; p < 4; p++) \
    G2L16(&sm[(buf) + ldo[p]], bp[p] + (size_t)(tt)*64); } while(0)

  const int agr0 = ((    quad) ^ (ln & 7)) * 8;
  const int agr1 = ((4 + quad) ^ (ln & 7)) * 8;
  int arow[4], brow[4];
  #pragma unroll
  for (int i = 0; i < 4; i++) arow[i] = (wm*64 + i*16 + ln) * 64;
  #pragma unroll
  for (int j = 0; j < 4; j++) brow[j] = (wn*64 + j*16 + ln) * 64;

  f32x4 acc[4][4] = {};
  STGA(0, 0); STGB(24576, 0); STGA(8192, 1);

  #pragma unroll
  for (int tt = 0; tt < 16; ++tt){
    const int a_cur = (tt % 3) * 8192;
    const int a_pf  = ((tt + 2) % 3) * 8192;
    const int b_cur = 24576 + (tt & 1) * 8192;
    const int b_pf  = 24576 + ((tt + 1) & 1) * 8192;

    if (tt < 15) { VM4(); } else { VM0(); }
    BARRAW(); SCHEDB();

    bf16x8 a01[2][2], bq[4][2];
    #pragma unroll
    for (int i = 0; i < 2; i++){
      a01[i][0] = *(const bf16x8*)&sm[a_cur + arow[i] + agr0];
      a01[i][1] = *(const bf16x8*)&sm[a_cur + arow[i] + agr1];
    }
    #pragma unroll
    for (int j = 0; j < 4; j++){
      bq[j][0] = *(const bf16x8*)&sm[b_cur + brow[j] + agr0];
      bq[j][1] = *(const bf16x8*)&sm[b_cur + brow[j] + agr1];
    }
    SCHEDB();
    if (tt < 15) STGB(b_pf, tt + 1);
    SCHEDB();
    WAIT_LGKM0(); SCHEDB();
    __builtin_amdgcn_s_setprio(1);
    #pragma unroll
    for (int i = 0; i < 2; i++)
      #pragma unroll
      for (int j = 0; j < 4; j++){
        MFMA_B16(acc[i][j], a01[i][0], bq[j][0]);
        MFMA_B16(acc[i][j], a01[i][1], bq[j][1]);
      }
    __builtin_amdgcn_s_setprio(0);

    bf16x8 a23[2][2];
    #pragma unroll
    for (int i = 0; i < 2; i++){
      a23[i][0] = *(const bf16x8*)&sm[a_cur + arow[2+i] + agr0];
      a23[i][1] = *(const bf16x8*)&sm[a_cur + arow[2+i] + agr1];
    }
    SCHEDB();
    if (tt < 14) STGA(a_pf, tt + 2);
    SCHEDB();
    WAIT_LGKM0(); SCHEDB();
    __builtin_amdgcn_s_setprio(1);
    #pragma unroll
    for (int i = 0; i < 2; i++)
      #pragma unroll
      for (int j = 0; j < 4; j++){
        MFMA_B16(acc[2+i][j], a23[i][0], bq[j][0]);
        MFMA_B16(acc[2+i][j], a23[i][1], bq[j][1]);
      }
    __builtin_amdgcn_s_setprio(0);
  }

  #pragma unroll
  for (int rb = 0; rb < 4; rb++)
    #pragma unroll
    for (int cb = 0; cb < 4; cb++)
      #pragma unroll
      for (int reg = 0; reg < 4; reg++){
        int row = m0 + wm*64 + rb*16 + quad*4 + reg;
        int col = n0 + wn*64 + cb*16 + ln;
        size_t off = (size_t)row*Dn + col;
        out[off] = acc[rb][cb][reg] + x[off];
      }
#undef STGA
#undef STGB
}

extern "C" void kernel_launch(void* const* d_in, const int* in_sizes, int n_in,
                              void* d_out, int out_size, void* d_ws, size_t ws_size,
                              hipStream_t stream){
  const float* x    = (const float*)d_in[0];
  const float* Wq   = (const float*)d_in[2];
  const float* Wk   = (const float*)d_in[3];
  const float* Wv   = (const float*)d_in[4];
  const float* Wout = (const float*)d_in[5];
  float* out = (float*)d_out;

  u16* ws = (u16*)d_ws;
  const size_t NW = (size_t)Dn * Dn;
  const size_t NX = (size_t)Bn * Sn * Dn;
  u16* wt  = ws;                // Wq^T(scaled),Wk^T,Wv^T,Wout^T
  u16* xb  = wt + 4*NW;         // x bf16
  u16* qb  = xb + NX;           // Q [b,h,s,d] (attn writes z in-place)
  u16* kb  = qb + NX;           // K [b,h,s,d]
  u16* vtb = kb + NX;           // Vt [b,h,d,s] (written directly by gemm_qkv)

  prep_kernel     <<<dim3(4096 + 1024), dim3(256), 0, stream>>>(x, Wq, Wk, Wv, Wout, xb, wt);
  gemm_qkv_kernel <<<dim3(1536), dim3(256), 0, stream>>>(xb, wt, qb, kb, vtb);
  attn_kernel     <<<dim3(8,16,4), dim3(512), 0, stream>>>(qb, kb, vtb, qb);
  gemm_out_kernel <<<dim3(512), dim3(256), 0, stream>>>(qb, wt + 3*NW, x, out);
}

// Round 9
// 252.300 us; speedup vs baseline: 2.2515x; 1.0455x over previous
//
#include <hip/hip_runtime.h>

#define Bn 4
#define Sn 2048
#define Dn 1024
#define Hn 16
#define DHn 64

typedef float f32x4 __attribute__((ext_vector_type(4)));
typedef short bf16x8 __attribute__((ext_vector_type(8)));
typedef unsigned short u16;
typedef unsigned int u32;
typedef unsigned short u16x8 __attribute__((ext_vector_type(8)));
typedef unsigned short u16x4 __attribute__((ext_vector_type(4)));
typedef u32 u32x4 __attribute__((ext_vector_type(4)));

union B8 { u32x4 u; bf16x8 s; u16x8 h; };

__device__ __forceinline__ u16 f2bf(float f){
  union { float f; u32 u; } v; v.f = f;
  return (u16)((v.u + 0x7fffu + ((v.u >> 16) & 1u)) >> 16);
}

// truncating pack: two fp32 -> {bf16(lo) | bf16(hi)<<16}. P>0 -> -0.2% uniform bias, negligible.
__device__ __forceinline__ u32 pack_bf2(float lo, float hi){
  union { float f; u32 u; } a, b;
  a.f = lo; b.f = hi;
  return __builtin_amdgcn_perm(b.u, a.u, 0x07060302u);
}

#if __has_builtin(__builtin_amdgcn_exp2f)
#define EXP2(x) __builtin_amdgcn_exp2f(x)
#define QSCALE 0.18033688011112042f   /* 0.125 * log2(e) */
#else
#define EXP2(x) __expf(x)
#define QSCALE 0.125f
#endif

#if __has_builtin(__builtin_amdgcn_global_load_lds)
#define G2L16(l, g) __builtin_amdgcn_global_load_lds((const __attribute__((address_space(1))) u32*)(g), \
                                                     (__attribute__((address_space(3))) u32*)(l), 16, 0, 0)
#else
#define G2L16(l, g) (*(bf16x8*)(l) = *(const bf16x8*)(g))
#endif

#define MFMA_B16(d, va, vb) (d) = __builtin_amdgcn_mfma_f32_16x16x32_bf16((va), (vb), (d), 0, 0, 0)
#define BARRAW() __builtin_amdgcn_s_barrier()
#define WAIT_LGKM0() asm volatile("s_waitcnt lgkmcnt(0)" ::: "memory")
#define VM4() asm volatile("s_waitcnt vmcnt(4)" ::: "memory")
#define VM0() asm volatile("s_waitcnt vmcnt(0)" ::: "memory")
#define SCHEDB() __builtin_amdgcn_sched_barrier(0)

// ---------------- merged prep: cast x (blocks 0..4095) + 4 weights (4096..5119) ----------------
__global__ void prep_kernel(const float* __restrict__ x,
                            const float* __restrict__ Wq, const float* __restrict__ Wk,
                            const float* __restrict__ Wv, const float* __restrict__ Wo,
                            u16* __restrict__ xb, u16* __restrict__ wt_all){
  __shared__ u16 tile[64*66];
  const int t = threadIdx.x;
  if (blockIdx.x < 4096){
    size_t i = ((size_t)blockIdx.x * 256 + t) * 8;
    float4 f0 = *(const float4*)(x + i);
    float4 f1 = *(const float4*)(x + i + 4);
    u16x8 o;
    o[0]=f2bf(f0.x); o[1]=f2bf(f0.y); o[2]=f2bf(f0.z); o[3]=f2bf(f0.w);
    o[4]=f2bf(f1.x); o[5]=f2bf(f1.y); o[6]=f2bf(f1.z); o[7]=f2bf(f1.w);
    *(u16x8*)(xb + i) = o;
    return;
  }
  const int wi = blockIdx.x - 4096;
  const int z = wi >> 8, r8 = wi & 255;
  const int k0 = (r8 >> 4) * 64, n0 = (r8 & 15) * 64;
  const float* w = (z == 0) ? Wq : (z == 1) ? Wk : (z == 2) ? Wv : Wo;
  const float scale = (z == 0) ? QSCALE : 1.0f;
  u16* wt = wt_all + (size_t)z * Dn * Dn;
  #pragma unroll
  for (int i = 0; i < 4; i++){
    int idx = i*256 + t;
    int r = idx >> 4, c4 = (idx & 15) * 4;
    float4 f = *(const float4*)(w + (size_t)(k0 + r)*Dn + n0 + c4);
    tile[r*66 + c4 + 0] = f2bf(f.x * scale);
    tile[r*66 + c4 + 1] = f2bf(f.y * scale);
    tile[r*66 + c4 + 2] = f2bf(f.z * scale);
    tile[r*66 + c4 + 3] = f2bf(f.w * scale);
  }
  __syncthreads();
  #pragma unroll
  for (int i = 0; i < 4; i++){
    int idx = i*256 + t;
    int nr = idx >> 4, kc4 = (idx & 15) * 4;
    u16x4 o;
    o[0] = tile[(kc4+0)*66 + nr];
    o[1] = tile[(kc4+1)*66 + nr];
    o[2] = tile[(kc4+2)*66 + nr];
    o[3] = tile[(kc4+3)*66 + nr];
    *(u16x4*)(wt + (size_t)(n0 + nr)*Dn + k0 + kc4) = o;
  }
}

// ---------------- QKV GEMM: 128^2 tile, BK=64, A-tri/B-dbuf, 1 barrier/K-tile ----------------
__launch_bounds__(256)
__global__ void gemm_qkv_kernel(const u16* __restrict__ xb, const u16* __restrict__ wt_all,
                                u16* __restrict__ qb, u16* __restrict__ kb, u16* __restrict__ vtb){
  __shared__ u16 sm[40960];   // 80 KB
  const int t = threadIdx.x;
  const int lane = t & 63, wave = t >> 6;
  const int ln = lane & 15, quad = lane >> 4;
  const int wm = wave >> 1, wn = wave & 1;

  // T1: XCD-chunked bijective swizzle (1536 = 8*192), m-outer n-inner within chunk
  const int lin = blockIdx.x;
  const int wg = (lin & 7) * 192 + (lin >> 3);
  const int zsel = wg >> 9;
  const int rem = wg & 511;
  const int m0 = (rem >> 3) * 128;
  const int n0 = (rem & 7) * 128;
  const u16* wt = wt_all + (size_t)zsel * Dn * Dn;

  const u16* ap[4]; const u16* bp[4]; int ldo[4];
  #pragma unroll
  for (int p = 0; p < 4; p++){
    int idx = p*256 + t;
    int r = idx >> 3, g = (idx & 7) ^ (r & 7);
    ap[p] = xb + (size_t)(m0 + r)*Dn + g*8;
    bp[p] = wt + (size_t)(n0 + r)*Dn + g*8;
    ldo[p] = idx * 8;
  }
#define STGA(buf, tt) do { _Pragma("unroll") for (int p = 0; p < 4; p++) \
    G2L16(&sm[(buf) + ldo[p]], ap[p] + (size_t)(tt)*64); } while(0)
#define STGB(buf, tt) do { _Pragma("unroll") for (int p = 0; p < 4; p++) \
    G2L16(&sm[(buf) + ldo[p]], bp[p] + (size_t)(tt)*64); } while(0)

  const int agr0 = ((    quad) ^ (ln & 7)) * 8;
  const int agr1 = ((4 + quad) ^ (ln & 7)) * 8;
  int arow[4], brow[4];
  #pragma unroll
  for (int i = 0; i < 4; i++) arow[i] = (wm*64 + i*16 + ln) * 64;
  #pragma unroll
  for (int j = 0; j < 4; j++) brow[j] = (wn*64 + j*16 + ln) * 64;

  f32x4 acc[4][4] = {};

  STGA(0, 0); STGB(24576, 0); STGA(8192, 1);

  #pragma unroll
  for (int tt = 0; tt < 16; ++tt){
    const int a_cur = (tt % 3) * 8192;
    const int a_pf  = ((tt + 2) % 3) * 8192;
    const int b_cur = 24576 + (tt & 1) * 8192;
    const int b_pf  = 24576 + ((tt + 1) & 1) * 8192;

    if (tt < 15) { VM4(); } else { VM0(); }
    BARRAW(); SCHEDB();

    bf16x8 a01[2][2], bq[4][2];
    #pragma unroll
    for (int i = 0; i < 2; i++){
      a01[i][0] = *(const bf16x8*)&sm[a_cur + arow[i] + agr0];
      a01[i][1] = *(const bf16x8*)&sm[a_cur + arow[i] + agr1];
    }
    #pragma unroll
    for (int j = 0; j < 4; j++){
      bq[j][0] = *(const bf16x8*)&sm[b_cur + brow[j] + agr0];
      bq[j][1] = *(const bf16x8*)&sm[b_cur + brow[j] + agr1];
    }
    SCHEDB();
    if (tt < 15) STGB(b_pf, tt + 1);
    SCHEDB();
    WAIT_LGKM0(); SCHEDB();
    __builtin_amdgcn_s_setprio(1);
    #pragma unroll
    for (int i = 0; i < 2; i++)
      #pragma unroll
      for (int j = 0; j < 4; j++){
        MFMA_B16(acc[i][j], a01[i][0], bq[j][0]);
        MFMA_B16(acc[i][j], a01[i][1], bq[j][1]);
      }
    __builtin_amdgcn_s_setprio(0);

    bf16x8 a23[2][2];
    #pragma unroll
    for (int i = 0; i < 2; i++){
      a23[i][0] = *(const bf16x8*)&sm[a_cur + arow[2+i] + agr0];
      a23[i][1] = *(const bf16x8*)&sm[a_cur + arow[2+i] + agr1];
    }
    SCHEDB();
    if (tt < 14) STGA(a_pf, tt + 2);
    SCHEDB();
    WAIT_LGKM0(); SCHEDB();
    __builtin_amdgcn_s_setprio(1);
    #pragma unroll
    for (int i = 0; i < 2; i++)
      #pragma unroll
      for (int j = 0; j < 4; j++){
        MFMA_B16(acc[2+i][j], a23[i][0], bq[j][0]);
        MFMA_B16(acc[2+i][j], a23[i][1], bq[j][1]);
      }
    __builtin_amdgcn_s_setprio(0);
  }

  __syncthreads();
  u16* Cs = sm;
  if (zsel < 2){
    u16* outp = (zsel == 0) ? qb : kb;
    #pragma unroll
    for (int rb = 0; rb < 4; rb++)
      #pragma unroll
      for (int cb = 0; cb < 4; cb++)
        #pragma unroll
        for (int reg = 0; reg < 4; reg++)
          Cs[(wm*64 + rb*16 + quad*4 + reg)*136 + wn*64 + cb*16 + ln] = f2bf(acc[rb][cb][reg]);
    __syncthreads();
    #pragma unroll
    for (int i = 0; i < 8; i++){
      int idx = i*256 + t;
      int r = idx >> 4, c8 = (idx & 15) * 8;
      bf16x8 vdat = *(const bf16x8*)&Cs[r*136 + c8];
      int row = m0 + r, bb = row >> 11, s = row & 2047;
      int col = n0 + c8, hh = col >> 6, d = col & 63;
      *(bf16x8*)(outp + (((size_t)bb*Hn + hh)*Sn + s)*DHn + d) = vdat;
    }
  } else {
    #pragma unroll
    for (int rb = 0; rb < 4; rb++)
      #pragma unroll
      for (int cb = 0; cb < 4; cb++){
        u16x4 o;
        #pragma unroll
        for (int reg = 0; reg < 4; reg++) o[reg] = f2bf(acc[rb][cb][reg]);
        *(u16x4*)&Cs[(wn*64 + cb*16 + ln)*136 + wm*64 + rb*16 + quad*4] = o;
      }
    __syncthreads();
    #pragma unroll
    for (int i = 0; i < 8; i++){
      int idx = i*256 + t;
      int c = idx >> 4, r8 = (idx & 15) * 8;
      bf16x8 vdat = *(const bf16x8*)&Cs[c*136 + r8];
      int col = n0 + c, hh = col >> 6, d = col & 63;
      int row = m0 + r8, bb = row >> 11, s = row & 2047;
      *(bf16x8*)(vtb + (((size_t)bb*Hn + hh)*DHn + d)*Sn + s) = vdat;
    }
  }
#undef STGA
#undef STGB
}

// ---------------- attention: r3 body (best measured: 77us, VGPR 64, 0 conflicts)
// + T5 setprio around MFMA clusters (m191: +4-7% attn; only cataloged technique
// absent from r3). No other change; numeric op order identical to r3.
__launch_bounds__(512, 4)
__global__ void attn_kernel(const u16* q, const u16* __restrict__ k,
                            const u16* __restrict__ vt, u16* z){
  __shared__ u16 Ks[2][64*64];   // [key][d], swizzled granules
  __shared__ u16 Vs[2][64*64];   // [d][key'] column-shuffled + swizzled granules
  const int t = threadIdx.x;
  const int wave = t >> 6, lane = t & 63;
  const int ln = lane & 15, quad = lane >> 4;
  const int lin = blockIdx.x + 8*(blockIdx.y + 16*blockIdx.z);
  const int wgs = (lin & 7)*64 + (lin >> 3);
  const int qt = wgs & 7, h = (wgs >> 3) & 15, b = wgs >> 7;
  const size_t bh = (size_t)b * Hn + h;
  const int q0 = qt*256 + wave*32;
  const u16* qp = q + bh * Sn * DHn;
  const u16* kp = k + bh * Sn * DHn;
  const u16* vp = vt + bh * DHn * Sn;

  bf16x8 qf[2][2];
  #pragma unroll
  for (int n = 0; n < 2; n++)
    #pragma unroll
    for (int kq = 0; kq < 2; kq++)
      qf[n][kq] = *(const bf16x8*)(qp + (size_t)(q0 + n*16 + ln)*DHn + kq*32 + quad*8);

  f32x4 zacc[4][2] = {};
  float dacc[2] = {0.f, 0.f};

  // staging: thread t stages granule a of row r for K and (shuffled) V
  const int r = t >> 3, a = t & 7;
  const int ksg = a >> 2, q1 = ((a&3)*2)&3, h1 = (a&3) >> 1;
  const int vc1 = ksg*32 + q1*8 + h1*4;
  const int vc2 = ksg*32 + (((q1+1)&3))*8 + h1*4;
  const int kpos  = r*64 + (a ^ (r&7))*8;
  const int vpos1 = r*64 + ((vc1>>3) ^ (r&7))*8 + (vc1 & 7);
  const int vpos2 = r*64 + ((vc2>>3) ^ (r&7))*8 + (vc2 & 7);

  bf16x8 rk, rv;
  rk = *(const bf16x8*)(kp + (size_t)r*DHn + a*8);
  rv = *(const bf16x8*)(vp + (size_t)r*Sn + a*8);
  {
    *(bf16x8*)&Ks[0][kpos] = rk;
    u16x4 lo = *(u16x4*)&rv;
    u16x4 hi = *((u16x4*)&rv + 1);
    *(u16x4*)&Vs[0][vpos1] = lo;
    *(u16x4*)&Vs[0][vpos2] = hi;
  }

  // swizzled read column offsets
  const int kg0 = ((    quad) ^ (ln & 7)) * 8;   // kq=0 / ks=0 granule
  const int kg1 = ((4 + quad) ^ (ln & 7)) * 8;   // kq=1 / ks=1 granule

  for (int kt = 0; kt < Sn/64; kt++){
    const int cur = kt & 1;
    __syncthreads();

    if (kt + 1 < Sn/64){
      rk = *(const bf16x8*)(kp + (size_t)((kt+1)*64 + r)*DHn + a*8);
      rv = *(const bf16x8*)(vp + (size_t)r*Sn + (kt+1)*64 + a*8);
    }
    const u16* Kc = Ks[cur];
    const u16* Vc = Vs[cur];

    #pragma unroll
    for (int ks = 0; ks < 2; ks++){
      f32x4 sacc[2][2] = {};
      #pragma unroll
      for (int kq = 0; kq < 2; kq++){
        const int kgo = kq ? kg1 : kg0;
        bf16x8 ka[2];
        #pragma unroll
        for (int m2 = 0; m2 < 2; m2++)
          ka[m2] = *(const bf16x8*)&Kc[((2*ks + m2)*16 + ln)*64 + kgo];
        __builtin_amdgcn_s_setprio(1);
        #pragma unroll
        for (int m2 = 0; m2 < 2; m2++)
          #pragma unroll
          for (int n = 0; n < 2; n++)
            sacc[m2][n] = __builtin_amdgcn_mfma_f32_16x16x32_bf16(ka[m2], qf[n][kq], sacc[m2][n], 0, 0, 0);
        __builtin_amdgcn_s_setprio(0);
      }
      B8 pb[2];
      #pragma unroll
      for (int n = 0; n < 2; n++){
        f32x4 s0 = sacc[0][n], s1 = sacc[1][n];
        float a0 = EXP2(s0[0]), a1 = EXP2(s0[1]), a2 = EXP2(s0[2]), a3 = EXP2(s0[3]);
        float b0 = EXP2(s1[0]), b1 = EXP2(s1[1]), b2 = EXP2(s1[2]), b3 = EXP2(s1[3]);
        dacc[n] += ((a0 + a1) + (a2 + a3)) + ((b0 + b1) + (b2 + b3));
        pb[n].u = (u32x4){pack_bf2(a0, a1), pack_bf2(a2, a3), pack_bf2(b0, b1), pack_bf2(b2, b3)};
      }
      const int vgo = ks ? kg1 : kg0;
      #pragma unroll
      for (int mtd = 0; mtd < 4; mtd++){
        bf16x8 va = *(const bf16x8*)&Vc[(mtd*16 + ln)*64 + vgo];
        __builtin_amdgcn_s_setprio(1);
        #pragma unroll
        for (int n = 0; n < 2; n++)
          zacc[mtd][n] = __builtin_amdgcn_mfma_f32_16x16x32_bf16(va, pb[n].s, zacc[mtd][n], 0, 0, 0);
        __builtin_amdgcn_s_setprio(0);
      }
    }

    if (kt + 1 < Sn/64){
      const int nxt = (kt+1) & 1;
      *(bf16x8*)&Ks[nxt][kpos] = rk;
      u16x4 lo = *(u16x4*)&rv;
      u16x4 hi = *((u16x4*)&rv + 1);
      *(u16x4*)&Vs[nxt][vpos1] = lo;
      *(u16x4*)&Vs[nxt][vpos2] = hi;
    }
  }

  float inv[2];
  #pragma unroll
  for (int n = 0; n < 2; n++){
    float d = dacc[n];
    d += __shfl_xor(d, 16, 64);
    d += __shfl_xor(d, 32, 64);
    inv[n] = 1.0f / d;
  }

  #pragma unroll
  for (int mtd = 0; mtd < 4; mtd++)
    #pragma unroll
    for (int n = 0; n < 2; n++){
      u16x4 o;
      #pragma unroll
      for (int j = 0; j < 4; j++) o[j] = f2bf(zacc[mtd][n][j] * inv[n]);
      *(u16x4*)(z + (bh*Sn + (size_t)(q0 + n*16 + ln))*DHn + mtd*16 + quad*4) = o;
    }
}

// ---------------- out = z * Wout^T + x: same A-tri/B-dbuf template, K-chunk 64 == head ----------------
__launch_bounds__(256)
__global__ void gemm_out_kernel(const u16* __restrict__ zb, const u16* __restrict__ wt,
                                const float* __restrict__ x, float* __restrict__ out){
  __shared__ u16 sm[40960];   // 80 KB
  const int t = threadIdx.x;
  const int lane = t & 63, wave = t >> 6;
  const int ln = lane & 15, quad = lane >> 4;
  const int wm = wave >> 1, wn = wave & 1;

  const int lin = blockIdx.x;
  const int wg = (lin & 7) * 64 + (lin >> 3);
  const int m0 = (wg >> 3) * 128;
  const int n0 = (wg & 7) * 128;

  const u16* ap[4]; const u16* bp[4]; int ldo[4];
  #pragma unroll
  for (int p = 0; p < 4; p++){
    int idx = p*256 + t;
    int r = idx >> 3, g = (idx & 7) ^ (r & 7);
    int row = m0 + r, bb = row >> 11, s = row & 2047;
    ap[p] = zb + ((size_t)bb*Hn*Sn + s)*DHn + g*8;    // head-0 base; head stride Sn*DHn
    bp[p] = wt + (size_t)(n0 + r)*Dn + g*8;
    ldo[p] = idx * 8;
  }
#define STGA(buf, tt) do { _Pragma("unroll") for (int p = 0; p < 4; p++) \
    G2L16(&sm[(buf) + ldo[p]], ap[p] + (size_t)(tt)*Sn*DHn); } while(0)
#define STGB(buf, tt) do { _Pragma("unroll") for (int p = 0; p < 4; p++) \
    G2L16(&sm[(buf) + ldo[p]], bp[p] + (size_t)(tt)*64); } while(0)

  const int agr0 = ((    quad) ^ (ln & 7)) * 8;
  const int agr1 = ((4 + quad) ^ (ln & 7)) * 8;
  int arow[4], brow[4];
  #pragma unroll
  for (int i = 0; i < 4; i++) arow[i] = (wm*64 + i*16 + ln) * 64;
  #pragma unroll
  for (int j = 0; j < 4; j++) brow[j] = (wn*64 + j*16 + ln) * 64;

  f32x4 acc[4][4] = {};
  STGA(0, 0); STGB(24576, 0); STGA(8192, 1);

  #pragma unroll
  for (int tt = 0; tt < 16; ++tt){
    const int a_cur = (tt % 3) * 8192;
    const int a_pf  = ((tt + 2) % 3) * 8192;
    const int b_cur = 24576 + (tt & 1) * 8192;
    const int b_pf  = 24576 + ((tt + 1) & 1) * 8192;

    if (tt < 15) { VM4(); } else { VM0(); }
    BARRAW(); SCHEDB();

    bf16x8 a01[2][2], bq[4][2];
    #pragma unroll
    for (int i = 0; i < 2; i++){
      a01[i][0] = *(const bf16x8*)&sm[a_cur + arow[i] + agr0];
      a01[i][1] = *(const bf16x8*)&sm[a_cur + arow[i] + agr1];
    }
    #pragma unroll
    for (int j = 0; j < 4; j++){
      bq[j][0] = *(const bf16x8*)&sm[b_cur + brow[j] + agr0];
      bq[j][1] = *(const bf16x8*)&sm[b_cur + brow[j] + agr1];
    }
    SCHEDB();
    if (tt < 15) STGB(b_pf, tt + 1);
    SCHEDB();
    WAIT_LGKM0(); SCHEDB();
    __builtin_amdgcn_s_setprio(1);
    #pragma unroll
    for (int i = 0; i < 2; i++)
      #pragma unroll
      for (int j = 0; j < 4; j++){
        MFMA_B16(acc[i][j], a01[i][0], bq[j][0]);
        MFMA_B16(acc[i][j], a01[i][1], bq[j][1]);
      }
    __builtin_amdgcn_s_setprio(0);

    bf16x8 a23[2][2];
    #pragma unroll
    for (int i = 0; i < 2; i++){
      a23[i][0] = *(const bf16x8*)&sm[a_cur + arow[2+i] + agr0];
      a23[i][1] = *(const bf16x8*)&sm[a_cur + arow[2+i] + agr1];
    }
    SCHEDB();
    if (tt < 14) STGA(a_pf, tt + 2);
    SCHEDB();
    WAIT_LGKM0(); SCHEDB();
    __builtin_amdgcn_s_setprio(1);
    #pragma unroll
    for (int i = 0; i < 2; i++)
      #pragma unroll
      for (int j = 0; j < 4; j++){
        MFMA_B16(acc[2+i][j], a23[i][0], bq[j][0]);
        MFMA_B16(acc[2+i][j], a23[i][1], bq[j][1]);
      }
    __builtin_amdgcn_s_setprio(0);
  }

  #pragma unroll
  for (int rb = 0; rb < 4; rb++)
    #pragma unroll
    for (int cb = 0; cb < 4; cb++)
      #pragma unroll
      for (int reg = 0; reg < 4; reg++){
        int row = m0 + wm*64 + rb*16 + quad*4 + reg;
        int col = n0 + wn*64 + cb*16 + ln;
        size_t off = (size_t)row*Dn + col;
        out[off] = acc[rb][cb][reg] + x[off];
      }
#undef STGA
#undef STGB
}

extern "C" void kernel_launch(void* const* d_in, const int* in_sizes, int n_in,
                              void* d_out, int out_size, void* d_ws, size_t ws_size,
                              hipStream_t stream){
  const float* x    = (const float*)d_in[0];
  const float* Wq   = (const float*)d_in[2];
  const float* Wk   = (const float*)d_in[3];
  const float* Wv   = (const float*)d_in[4];
  const float* Wout = (const float*)d_in[5];
  float* out = (float*)d_out;

  u16* ws = (u16*)d_ws;
  const size_t NW = (size_t)Dn * Dn;
  const size_t NX = (size_t)Bn * Sn * Dn;
  u16* wt  = ws;                // Wq^T(scaled),Wk^T,Wv^T,Wout^T
  u16* xb  = wt + 4*NW;         // x bf16
  u16* qb  = xb + NX;           // Q [b,h,s,d] (attn writes z in-place)
  u16* kb  = qb + NX;           // K [b,h,s,d]
  u16* vtb = kb + NX;           // Vt [b,h,d,s] (written directly by gemm_qkv)

  prep_kernel     <<<dim3(4096 + 1024), dim3(256), 0, stream>>>(x, Wq, Wk, Wv, Wout, xb, wt);
  gemm_qkv_kernel <<<dim3(1536), dim3(256), 0, stream>>>(xb, wt, qb, kb, vtb);
  attn_kernel     <<<dim3(8,16,4), dim3(512), 0, stream>>>(qb, kb, vtb, qb);
  gemm_out_kernel <<<dim3(512), dim3(256), 0, stream>>>(qb, wt + 3*NW, x, out);
}